// Round 12
// baseline (355.217 us; speedup 1.0000x reference)
//
#include <hip/hip_runtime.h>
#include <math.h>

#define NN 50000
#define NP 50048   // padded to 64-row multiple (782 * 64)
#define NB (NP / 64)                 // 782 row-blocks
#define SCAN_NB ((NN + 255) / 256)   // 196
#define NBKT ((NN + 255) / 256)      // 196 dst-buckets of 256 rows

typedef unsigned short u16;
typedef unsigned int u32;

typedef __bf16 bf16x8 __attribute__((ext_vector_type(8)));
typedef float f32x4 __attribute__((ext_vector_type(4)));

__device__ __forceinline__ u16 f2bf(float f) {
    u32 u = __float_as_uint(f);
    u32 r = (u + 0x7FFFu + ((u >> 16) & 1u)) >> 16;
    return (u16)r;
}
__device__ __forceinline__ float bf2f_lo(u32 v) { return __uint_as_float(v << 16); }
__device__ __forceinline__ float bf2f_hi(u32 v) { return __uint_as_float(v & 0xFFFF0000u); }

// ============ bucketed CSR build ============
__global__ __launch_bounds__(256) void k_binA(const int* __restrict__ dst, int E,
                                              int* __restrict__ bcntT, int nblk) {
    __shared__ int h[NBKT];
    for (int i = threadIdx.x; i < NBKT; i += 256) h[i] = 0;
    __syncthreads();
    int base = blockIdx.x * 4096;
#pragma unroll
    for (int i = 0; i < 16; i++) {
        int e = base + i * 256 + threadIdx.x;
        if (e < E) atomicAdd(&h[dst[e] >> 8], 1);
    }
    __syncthreads();
    for (int i = threadIdx.x; i < NBKT; i += 256) bcntT[i * nblk + blockIdx.x] = h[i];
}

__global__ __launch_bounds__(256) void k_binT(const int* __restrict__ bcntT,
        int* __restrict__ colpre, int* __restrict__ tot, int nblk) {
    __shared__ int sh[256];
    int k = blockIdx.x, t = threadIdx.x;
    int v = (t < nblk) ? bcntT[k * nblk + t] : 0;
    sh[t] = v; __syncthreads();
    int inc = v;
    for (int o = 1; o < 256; o <<= 1) {
        int p = (t >= o) ? sh[t - o] : 0;
        __syncthreads();
        inc += p; sh[t] = inc;
        __syncthreads();
    }
    if (t < nblk) colpre[k * nblk + t] = inc - v;
    if (t == 255) tot[k] = inc;
}

__global__ __launch_bounds__(256) void k_scan_tot(const int* __restrict__ tot,
                                                  int* __restrict__ bstart, int E) {
    __shared__ int sh[256];
    int t = threadIdx.x;
    int v = (t < NBKT) ? tot[t] : 0;
    sh[t] = v; __syncthreads();
    int inc = v;
    for (int o = 1; o < 256; o <<= 1) {
        int p = (t >= o) ? sh[t - o] : 0;
        __syncthreads();
        inc += p; sh[t] = inc;
        __syncthreads();
    }
    if (t < NBKT) bstart[t] = inc - v;
    if (t == NBKT - 1) bstart[NBKT] = E;
}

__global__ __launch_bounds__(256) void k_binB(const int* __restrict__ src,
        const int* __restrict__ dst, int E, const int* __restrict__ bstart,
        const int* __restrict__ colpre, int nblk, u32* __restrict__ ebuf) {
    __shared__ int h[NBKT];
    __shared__ int base[NBKT];
    int b = blockIdx.x;
    for (int i = threadIdx.x; i < NBKT; i += 256) {
        h[i] = 0;
        base[i] = bstart[i] + colpre[i * nblk + b];
    }
    __syncthreads();
    int bb = b * 4096;
#pragma unroll
    for (int i = 0; i < 16; i++) {
        int e = bb + i * 256 + threadIdx.x;
        if (e < E) {
            int d = dst[e];
            int k = d >> 8;
            int r = atomicAdd(&h[k], 1);
            ebuf[base[k] + r] = ((u32)d << 16) | (u32)src[e];
        }
    }
}

// per-bucket: cnt + dis + bsum + degree-histogram (LDS-aggregated)
__global__ __launch_bounds__(256) void k_bcnt_bsum_dis(const u32* __restrict__ ebuf,
        const int* __restrict__ bstart, int* __restrict__ cnt, float* __restrict__ dis,
        int* __restrict__ bsum, int* __restrict__ dhist, int n) {
    __shared__ int h[256];
    __shared__ int red[256];
    int k = blockIdx.x, t = threadIdx.x;
    h[t] = 0; __syncthreads();
    int beg = bstart[k], end = bstart[k + 1];
    for (int j = beg + t; j < end; j += 256)
        atomicAdd(&h[(ebuf[j] >> 16) & 255], 1);
    __syncthreads();
    int r = k * 256 + t;
    int d = h[t];
    bool valid = (r < n);
    if (valid) { cnt[r] = d; dis[r] = rsqrtf((float)d + 1.0f); }
    red[t] = valid ? d : 0;
    __syncthreads();
    // reuse h as degree-bin histogram
    h[t] = 0; __syncthreads();
    if (valid) atomicAdd(&h[min(d, 255)], 1);
    __syncthreads();
    if (h[t] > 0) atomicAdd(&dhist[t], h[t]);
    for (int off = 128; off; off >>= 1) {
        if (t < off) red[t] += red[t + off];
        __syncthreads();
    }
    if (t == 0) bsum[k] = red[0];
}

// scan bsum (196) + scan dhist (256) -> dcur starting cursors
__global__ __launch_bounds__(256) void k_scan_bsum_dhist(int* __restrict__ bsum, int nb,
        const int* __restrict__ dhist, int* __restrict__ dcur) {
    __shared__ int sh[256];
    int t = threadIdx.x;
    int v0 = (t < nb) ? bsum[t] : 0;
    sh[t] = v0; __syncthreads();
    int inc = v0;
    for (int off = 1; off < 256; off <<= 1) {
        int o = (t >= off) ? sh[t - off] : 0;
        __syncthreads();
        inc += o; sh[t] = inc;
        __syncthreads();
    }
    if (t < nb) bsum[t] = inc - v0;
    __syncthreads();
    int w0 = dhist[t];
    sh[t] = w0; __syncthreads();
    int winc = w0;
    for (int off = 1; off < 256; off <<= 1) {
        int o = (t >= off) ? sh[t - off] : 0;
        __syncthreads();
        winc += o; sh[t] = winc;
        __syncthreads();
    }
    dcur[t] = winc - w0;
}

// scan-finish + P0 prescale + perm placement + bucket adj fill (same 256-row blocking)
__global__ __launch_bounds__(256) void k_sfpb(const int* __restrict__ cnt,
        const int* __restrict__ bpre, int* __restrict__ rowstart,
        const float* __restrict__ x, const float* __restrict__ dis,
        float* __restrict__ p0, const u32* __restrict__ ebuf,
        const int* __restrict__ bstart, u16* __restrict__ adj,
        int* __restrict__ dcur, int* __restrict__ perm, int n, int E) {
    __shared__ int sh[256];
    __shared__ int cur[256];
    int b = blockIdx.x, t = threadIdx.x;
    int i = b * 256 + t;
    int v0 = (i < n) ? cnt[i] : 0;
    sh[t] = v0; __syncthreads();
    int inc = v0;
    for (int off = 1; off < 256; off <<= 1) {
        int o = (t >= off) ? sh[t - off] : 0;
        __syncthreads();
        inc += o; sh[t] = inc;
        __syncthreads();
    }
    int rs = bpre[b] + inc - v0;
    if (i < n) {
        rowstart[i] = rs;
        float dv = dis[i];
        ((float4*)p0)[i] = make_float4(dv * x[i * 3], dv * x[i * 3 + 1], dv * x[i * 3 + 2], 0.f);
        int pos = atomicAdd(&dcur[min(v0, 255)], 1);
        perm[pos] = i;
    }
    if (b == gridDim.x - 1 && t == 0) rowstart[n] = E;
    cur[t] = rs;
    __syncthreads();
    int beg = bstart[b], end = bstart[b + 1];
    for (int j = beg + t; j < end; j += 256) {
        u32 e = ebuf[j];
        int p = atomicAdd(&cur[(e >> 16) & 255], 1);
        adj[p] = (u16)(e & 0xFFFF);
    }
}

// ============ weight prep ============
__global__ void k_wprep_all(const float* __restrict__ W2, const float* __restrict__ W3,
                            u16* __restrict__ w2h, u16* __restrict__ w2l,
                            u16* __restrict__ w3h, u16* __restrict__ w3l) {
    int idx = blockIdx.x * 256 + threadIdx.x;
    float w; u16* ph; u16* pl; int slot;
    if (idx < 64 * 64) {
        int o = idx >> 6, k = idx & 63;
        w = W2[k * 64 + o]; ph = w2h; pl = w2l; slot = o * 64 + k;
    } else if (idx < 64 * 64 + 256 * 64) {
        int i2 = idx - 64 * 64;
        int o = i2 >> 6, k = i2 & 63;
        w = W3[k * 256 + o]; ph = w3h; pl = w3l; slot = o * 64 + k;
    } else return;
    u16 h = f2bf(w);
    float hf = __uint_as_float((u32)h << 16);
    ph[slot] = h;
    pl[slot] = f2bf(w - hf);
}

// ============ gathers (degree-sorted via perm) ============
__global__ void k_gather3(const int* __restrict__ perm, const int* __restrict__ rowstart,
                          const u16* __restrict__ adj, const float* __restrict__ p0,
                          const float* __restrict__ dis, float* __restrict__ z, int n) {
    int gid = blockIdx.x * 256 + threadIdx.x;
    if (gid >= n) return;
    int row = perm[gid];
    const float4* P4 = (const float4*)p0;
    float4 v = P4[row];
    float a0 = v.x, a1 = v.y, a2 = v.z;
    int beg = rowstart[row], end = rowstart[row + 1];
    for (int j = beg; j < end; j++) {
        int s = (int)__builtin_nontemporal_load(adj + j);
        float4 w = P4[s];
        a0 += w.x; a1 += w.y; a2 += w.z;
    }
    float dv = dis[row];
    z[row * 3] = dv * a0; z[row * 3 + 1] = dv * a1; z[row * 3 + 2] = dv * a2;
}

__global__ __launch_bounds__(256) void k_gather64_bf16(const int* __restrict__ perm,
        const int* __restrict__ rowstart, const u16* __restrict__ adj,
        const u16* __restrict__ pb, const float* __restrict__ dis,
        u16* __restrict__ zb, int n) {
    int gid = blockIdx.x * 16 + (threadIdx.x >> 4);
    int lane = threadIdx.x & 15;
    if (gid >= n) return;
    int row = perm[gid];
    uint2 v = *((const uint2*)(pb + ((size_t)row << 6)) + lane);
    float a0 = bf2f_lo(v.x), a1 = bf2f_hi(v.x), a2 = bf2f_lo(v.y), a3 = bf2f_hi(v.y);
    int beg = rowstart[row], end = rowstart[row + 1];
    int j = beg;
    for (; j + 3 < end; j += 4) {
        int s0 = (int)__builtin_nontemporal_load(adj + j);
        int s1 = (int)__builtin_nontemporal_load(adj + j + 1);
        int s2 = (int)__builtin_nontemporal_load(adj + j + 2);
        int s3 = (int)__builtin_nontemporal_load(adj + j + 3);
        uint2 v0 = *((const uint2*)(pb + ((size_t)s0 << 6)) + lane);
        uint2 v1 = *((const uint2*)(pb + ((size_t)s1 << 6)) + lane);
        uint2 v2 = *((const uint2*)(pb + ((size_t)s2 << 6)) + lane);
        uint2 v3 = *((const uint2*)(pb + ((size_t)s3 << 6)) + lane);
        a0 += (bf2f_lo(v0.x) + bf2f_lo(v1.x)) + (bf2f_lo(v2.x) + bf2f_lo(v3.x));
        a1 += (bf2f_hi(v0.x) + bf2f_hi(v1.x)) + (bf2f_hi(v2.x) + bf2f_hi(v3.x));
        a2 += (bf2f_lo(v0.y) + bf2f_lo(v1.y)) + (bf2f_lo(v2.y) + bf2f_lo(v3.y));
        a3 += (bf2f_hi(v0.y) + bf2f_hi(v1.y)) + (bf2f_hi(v2.y) + bf2f_hi(v3.y));
    }
    for (; j < end; j++) {
        int s = (int)__builtin_nontemporal_load(adj + j);
        uint2 v0 = *((const uint2*)(pb + ((size_t)s << 6)) + lane);
        a0 += bf2f_lo(v0.x); a1 += bf2f_hi(v0.x);
        a2 += bf2f_lo(v0.y); a3 += bf2f_hi(v0.y);
    }
    float dv = dis[row];
    uint2 o;
    o.x = (u32)f2bf(a0 * dv) | ((u32)f2bf(a1 * dv) << 16);
    o.y = (u32)f2bf(a2 * dv) | ((u32)f2bf(a3 * dv) << 16);
    ((uint2*)(zb + ((size_t)row << 6)))[lane] = o;
}

__global__ void k_gather1_final(const int* __restrict__ perm, const int* __restrict__ rowstart,
                                const u16* __restrict__ adj, const float* __restrict__ q,
                                const float* __restrict__ dis, const float* __restrict__ b4,
                                float* __restrict__ out, int n) {
    int gid = blockIdx.x * 256 + threadIdx.x;
    if (gid >= n) return;
    int row = perm[gid];
    float acc = q[row];
    int beg = rowstart[row], end = rowstart[row + 1];
    for (int j = beg; j < end; j++)
        acc += q[(int)__builtin_nontemporal_load(adj + j)];
    float v = dis[row] * acc + b4[0];
    out[row] = 1.f / (1.f + expf(-v));
}

// ============ MFMA GEMM + per-block stats partials ============
__global__ __launch_bounds__(256) void k_mgemm(const u16* __restrict__ zb,
        const u16* __restrict__ wth, const u16* __restrict__ wtl,
        u16* __restrict__ t, int tstride,
        double* __restrict__ pS, double* __restrict__ pQ) {
    const int wv = threadIdx.x >> 6, lane = threadIdx.x & 63;
    const int lc = lane & 15, lk = lane >> 4;
    const int r0 = blockIdx.x * 64;
    const int col = blockIdx.y * 64 + wv * 16 + lc;

    const bf16x8* wh = (const bf16x8*)(wth + (size_t)col * 64 + lk * 8);
    const bf16x8* wl = (const bf16x8*)(wtl + (size_t)col * 64 + lk * 8);
    bf16x8 bh0 = wh[0], bh1 = wh[4];
    bf16x8 bl0 = wl[0], bl1 = wl[4];

    f32x4 acc[4] = {};
#pragma unroll
    for (int rt = 0; rt < 4; rt++) {
        const bf16x8* ap = (const bf16x8*)(zb + (size_t)(r0 + rt * 16 + lc) * 64 + lk * 8);
        bf16x8 a0 = ap[0], a1 = ap[4];
        acc[rt] = __builtin_amdgcn_mfma_f32_16x16x32_bf16(a0, bh0, acc[rt], 0, 0, 0);
        acc[rt] = __builtin_amdgcn_mfma_f32_16x16x32_bf16(a1, bh1, acc[rt], 0, 0, 0);
        acc[rt] = __builtin_amdgcn_mfma_f32_16x16x32_bf16(a0, bl0, acc[rt], 0, 0, 0);
        acc[rt] = __builtin_amdgcn_mfma_f32_16x16x32_bf16(a1, bl1, acc[rt], 0, 0, 0);
    }
#pragma unroll
    for (int rt = 0; rt < 4; rt++) {
        int rowb = r0 + rt * 16 + lk * 4;
#pragma unroll
        for (int rg = 0; rg < 4; rg++)
            t[(size_t)(rowb + rg) * tstride + col] = f2bf(acc[rt][rg]);
    }
    float s = 0.f, q = 0.f;
#pragma unroll
    for (int rt = 0; rt < 4; rt++)
#pragma unroll
        for (int rg = 0; rg < 4; rg++) { float v = acc[rt][rg]; s += v; q += v * v; }
    s += __shfl_xor(s, 16); q += __shfl_xor(q, 16);
    s += __shfl_xor(s, 32); q += __shfl_xor(q, 32);
    if (lane < 16) {
        pS[(size_t)col * NB + blockIdx.x] = (double)s;
        pQ[(size_t)col * NB + blockIdx.x] = (double)q;
    }
}

__global__ __launch_bounds__(256) void k_gemm3_stats(const float* __restrict__ z,
        const float* __restrict__ W, u16* __restrict__ t,
        double* __restrict__ pS, double* __restrict__ pQ, int n) {
    __shared__ float sH[64 * 4];
    __shared__ float sW[3 * 64];
    __shared__ double red[2 * 16 * 64];
    const int tid = threadIdx.x;
    const int r0 = blockIdx.x * 64;
    for (int i = tid; i < 192; i += 256) {
        int r = i / 3, c = i - r * 3;
        sH[r * 4 + c] = (r0 + r < n) ? z[(size_t)(r0 + r) * 3 + c] : 0.f;
    }
    if (tid < 48) ((float4*)sW)[tid] = ((const float4*)W)[tid];
    __syncthreads();
    const int tx = tid & 15, ty = tid >> 4;
    float4 acc[4];
#pragma unroll
    for (int r = 0; r < 4; r++) acc[r] = make_float4(0.f, 0.f, 0.f, 0.f);
    const float4* sW4 = (const float4*)sW;
#pragma unroll
    for (int k = 0; k < 3; k++) {
        float4 wv = sW4[k * 16 + tx];
#pragma unroll
        for (int r = 0; r < 4; r++) {
            float hs = sH[(ty * 4 + r) * 4 + k];
            acc[r].x += hs * wv.x; acc[r].y += hs * wv.y;
            acc[r].z += hs * wv.z; acc[r].w += hs * wv.w;
        }
    }
#pragma unroll
    for (int r = 0; r < 4; r++) {
        int row = r0 + ty * 4 + r;
        if (row < n) {
            uint2 o;
            o.x = (u32)f2bf(acc[r].x) | ((u32)f2bf(acc[r].y) << 16);
            o.y = (u32)f2bf(acc[r].z) | ((u32)f2bf(acc[r].w) << 16);
            *(uint2*)&t[(size_t)row * 64 + tx * 4] = o;
        }
    }
    double* redS = red;
    double* redQ = red + 16 * 64;
    double s0 = 0, s1 = 0, s2 = 0, s3 = 0, q0 = 0, q1 = 0, q2 = 0, q3 = 0;
#pragma unroll
    for (int r = 0; r < 4; r++) {
        s0 += acc[r].x; q0 += (double)acc[r].x * acc[r].x;
        s1 += acc[r].y; q1 += (double)acc[r].y * acc[r].y;
        s2 += acc[r].z; q2 += (double)acc[r].z * acc[r].z;
        s3 += acc[r].w; q3 += (double)acc[r].w * acc[r].w;
    }
    int base = ty * 64 + tx * 4;
    redS[base + 0] = s0; redS[base + 1] = s1; redS[base + 2] = s2; redS[base + 3] = s3;
    redQ[base + 0] = q0; redQ[base + 1] = q1; redQ[base + 2] = q2; redQ[base + 3] = q3;
    __syncthreads();
    if (ty == 0) {
#pragma unroll
        for (int jj = 0; jj < 4; jj++) {
            int c = tx * 4 + jj;
            double S = 0, Q = 0;
            for (int g = 0; g < 16; g++) { S += redS[g * 64 + c]; Q += redQ[g * 64 + c]; }
            pS[(size_t)c * NB + blockIdx.x] = S;
            pQ[(size_t)c * NB + blockIdx.x] = Q;
        }
    }
}

template<int F>
__global__ __launch_bounds__(256) void k_stats_fin(const double* __restrict__ pS,
        const double* __restrict__ pQ, const float* __restrict__ g,
        const float* __restrict__ be, double* __restrict__ st, int n) {
    __shared__ double shS[256], shQ[256];
    int c = blockIdx.x, t = threadIdx.x;
    double s = 0, q = 0;
    for (int i = t; i < NB; i += 256) {
        s += pS[(size_t)c * NB + i];
        q += pQ[(size_t)c * NB + i];
    }
    shS[t] = s; shQ[t] = q;
    __syncthreads();
    for (int off = 128; off; off >>= 1) {
        if (t < off) { shS[t] += shS[t + off]; shQ[t] += shQ[t + off]; }
        __syncthreads();
    }
    if (t == 0) {
        double mean = shS[0] / n;
        double var = shQ[0] / n - mean * mean;
        if (var < 0.0) var = 0.0;
        double mult = (double)g[c] / sqrt(var + 1e-5);
        st[2 * F + c] = mult;
        st[3 * F + c] = (double)be[c] - mult * mean;
    }
}

// p_bf16 = dis[v] * lrelu(mult*t + add)   (F=64)
__global__ void k_apply64(const u16* __restrict__ t, const float* __restrict__ dis,
                          const double* __restrict__ st, u16* __restrict__ p, int n) {
    int idx = blockIdx.x * 256 + threadIdx.x;
    if (idx >= n * 16) return;
    int row = idx >> 4, c = (idx & 15) * 4;
    uint2 v = ((const uint2*)t)[idx];
    float f0 = bf2f_lo(v.x), f1 = bf2f_hi(v.x), f2 = bf2f_lo(v.y), f3 = bf2f_hi(v.y);
    float m0 = (float)st[128 + c], m1 = (float)st[129 + c],
          m2 = (float)st[130 + c], m3 = (float)st[131 + c];
    float a0 = (float)st[192 + c], a1 = (float)st[193 + c],
          a2 = (float)st[194 + c], a3 = (float)st[195 + c];
    float r0 = m0 * f0 + a0; r0 = r0 > 0.f ? r0 : 0.1f * r0;
    float r1 = m1 * f1 + a1; r1 = r1 > 0.f ? r1 : 0.1f * r1;
    float r2 = m2 * f2 + a2; r2 = r2 > 0.f ? r2 : 0.1f * r2;
    float r3 = m3 * f3 + a3; r3 = r3 > 0.f ? r3 : 0.1f * r3;
    float dv = dis[row];
    uint2 o;
    o.x = (u32)f2bf(r0 * dv) | ((u32)f2bf(r1 * dv) << 16);
    o.y = (u32)f2bf(r2 * dv) | ((u32)f2bf(r3 * dv) << 16);
    ((uint2*)p)[idx] = o;
}

// layer3 apply + layer4 dot fused (t bf16, stride 256)
__global__ void k_apply3_dot(const u16* __restrict__ t, const double* __restrict__ st,
                             const float* __restrict__ dis, const float* __restrict__ W4,
                             float* __restrict__ q, int n) {
    int row = blockIdx.x * 4 + (threadIdx.x >> 6);
    int lane = threadIdx.x & 63;
    if (row >= n) return;
    uint2 v = ((const uint2*)t)[(size_t)row * 64 + lane];
    float f0 = bf2f_lo(v.x), f1 = bf2f_hi(v.x), f2 = bf2f_lo(v.y), f3 = bf2f_hi(v.y);
    int c = lane * 4;
    float m0 = (float)st[512 + c], m1 = (float)st[513 + c],
          m2 = (float)st[514 + c], m3 = (float)st[515 + c];
    float a0 = (float)st[768 + c], a1 = (float)st[769 + c],
          a2 = (float)st[770 + c], a3 = (float)st[771 + c];
    float b0 = m0 * f0 + a0; b0 = b0 > 0.f ? b0 : 0.1f * b0;
    float b1 = m1 * f1 + a1; b1 = b1 > 0.f ? b1 : 0.1f * b1;
    float b2 = m2 * f2 + a2; b2 = b2 > 0.f ? b2 : 0.1f * b2;
    float b3 = m3 * f3 + a3; b3 = b3 > 0.f ? b3 : 0.1f * b3;
    float4 w = ((const float4*)W4)[lane];
    float s = b0 * w.x + b1 * w.y + b2 * w.z + b3 * w.w;
#pragma unroll
    for (int off = 32; off; off >>= 1) s += __shfl_down(s, off);
    if (lane == 0) q[row] = dis[row] * s;
}

extern "C" void kernel_launch(void* const* d_in, const int* in_sizes, int n_in,
                              void* d_out, int out_size, void* d_ws, size_t ws_size,
                              hipStream_t stream) {
    const float* x  = (const float*)d_in[0];
    const int*   ei = (const int*)d_in[1];
    const int E = in_sizes[1] / 2;
    const int* src = ei;
    const int* dst = ei + E;
    const float* W1 = (const float*)d_in[2];
    const float* g1 = (const float*)d_in[4];
    const float* be1= (const float*)d_in[5];
    const float* W2 = (const float*)d_in[6];
    const float* g2 = (const float*)d_in[8];
    const float* be2= (const float*)d_in[9];
    const float* W3 = (const float*)d_in[10];
    const float* g3 = (const float*)d_in[12];
    const float* be3= (const float*)d_in[13];
    const float* W4 = (const float*)d_in[14];
    const float* b4 = (const float*)d_in[15];
    float* out = (float*)d_out;

    const int nblk = (E + 4095) / 4096;   // 196 for E=800k

    // workspace layout
    u16*   T    = (u16*)d_ws;                       // NP*256 bf16
    u16*   P    = T + (size_t)NP * 256;             // NN*64  bf16
    u16*   Zb   = P + (size_t)NN * 64;              // NP*64  bf16 (pad rows zeroed)
    u16*   Wt2h = Zb + (size_t)NP * 64;             // 64*64
    u16*   Wt2l = Wt2h + 64 * 64;
    u16*   Wt3h = Wt2l + 64 * 64;                   // 256*64
    u16*   Wt3l = Wt3h + 256 * 64;
    double* st  = (double*)(Wt3l + 256 * 64);       // 3*1024 doubles
    double *st0 = st, *st1 = st + 1024, *st2 = st + 2048;
    double* pS  = st + 3 * 1024;                    // 256*NB
    double* pQ  = pS + (size_t)256 * NB;            // 256*NB
    float* Z3   = (float*)(pQ + (size_t)256 * NB);  // NN*3
    float* P0   = Z3 + NN * 3;                      // NN*4
    float* Q    = P0 + NN * 4;                      // NN
    float* dis  = Q + NN;                           // NN
    int* cnt      = (int*)(dis + NN);               // NN
    int* rowstart = cnt + NN;                       // NN+1 (+pad)
    int* perm     = rowstart + NN + 8;              // NN
    u16* adj      = (u16*)(perm + NN);              // E u16
    int* bsum     = (int*)(adj + E + (E & 1));      // SCAN_NB (+pad)
    u32* ebuf     = (u32*)(bsum + SCAN_NB + 4);     // E packed edges
    int* bcntT    = (int*)(ebuf + E);               // NBKT*nblk
    int* colpre   = bcntT + NBKT * nblk;            // NBKT*nblk
    int* tot      = colpre + NBKT * nblk;           // NBKT
    int* bstart   = tot + NBKT + 4;                 // NBKT+1
    int* dhist    = bstart + NBKT + 4;              // 256
    int* dcur     = dhist + 256;                    // 256

    hipMemsetAsync(Zb + (size_t)NN * 64, 0, (size_t)(NP - NN) * 64 * sizeof(u16), stream);
    hipMemsetAsync(dhist, 0, 256 * sizeof(int), stream);

    // bucketed CSR build + degree sort
    k_binA<<<nblk, 256, 0, stream>>>(dst, E, bcntT, nblk);
    k_binT<<<NBKT, 256, 0, stream>>>(bcntT, colpre, tot, nblk);
    k_scan_tot<<<1, 256, 0, stream>>>(tot, bstart, E);
    k_binB<<<nblk, 256, 0, stream>>>(src, dst, E, bstart, colpre, nblk, ebuf);
    k_bcnt_bsum_dis<<<NBKT, 256, 0, stream>>>(ebuf, bstart, cnt, dis, bsum, dhist, NN);
    k_scan_bsum_dhist<<<1, 256, 0, stream>>>(bsum, SCAN_NB, dhist, dcur);
    k_sfpb<<<SCAN_NB, 256, 0, stream>>>(cnt, bsum, rowstart, x, dis, P0, ebuf, bstart,
                                        adj, dcur, perm, NN, E);
    k_wprep_all<<<(64 * 64 + 256 * 64 + 255) / 256, 256, 0, stream>>>(W2, W3, Wt2h, Wt2l, Wt3h, Wt3l);

    const int rows_grid = (NN + 255) / 256;
    const int g16_grid  = (NN + 15) / 16;
    const int wave4_grid = (NN + 3) / 4;
    const int app_grid = (NN * 16 + 255) / 256;

    // ---- Layer 1 ----
    k_gather3<<<rows_grid, 256, 0, stream>>>(perm, rowstart, adj, P0, dis, Z3, NN);
    k_gemm3_stats<<<NB, 256, 0, stream>>>(Z3, W1, T, pS, pQ, NN);
    k_stats_fin<64><<<64, 256, 0, stream>>>(pS, pQ, g1, be1, st0, NN);
    k_apply64<<<app_grid, 256, 0, stream>>>(T, dis, st0, P, NN);

    // ---- Layer 2 ----
    k_gather64_bf16<<<g16_grid, 256, 0, stream>>>(perm, rowstart, adj, P, dis, Zb, NN);
    k_mgemm<<<dim3(NB, 1), 256, 0, stream>>>(Zb, Wt2h, Wt2l, T, 64, pS, pQ);
    k_stats_fin<64><<<64, 256, 0, stream>>>(pS, pQ, g2, be2, st1, NN);
    k_apply64<<<app_grid, 256, 0, stream>>>(T, dis, st1, P, NN);

    // ---- Layer 3 ----
    k_gather64_bf16<<<g16_grid, 256, 0, stream>>>(perm, rowstart, adj, P, dis, Zb, NN);
    k_mgemm<<<dim3(NB, 4), 256, 0, stream>>>(Zb, Wt3h, Wt3l, T, 256, pS, pQ);
    k_stats_fin<256><<<256, 256, 0, stream>>>(pS, pQ, g3, be3, st2, NN);

    // ---- Layer 3 apply + Layer 4 dot, then scalar gather + sigmoid ----
    k_apply3_dot<<<wave4_grid, 256, 0, stream>>>(T, st2, dis, W4, Q, NN);
    k_gather1_final<<<rows_grid, 256, 0, stream>>>(perm, rowstart, adj, Q, dis, b4, out, NN);
}

// Round 13
// 222.310 us; speedup vs baseline: 1.5978x; 1.5978x over previous
//
#include <hip/hip_runtime.h>
#include <math.h>

#define NN 50000
#define NP 50048   // padded to 64-row multiple (782 * 64)
#define NB (NP / 64)                 // 782 row-blocks
#define SCAN_NB ((NN + 255) / 256)   // 196
#define NBKT ((NN + 255) / 256)      // 196 dst-buckets of 256 rows

typedef unsigned short u16;
typedef unsigned int u32;

typedef __bf16 bf16x8 __attribute__((ext_vector_type(8)));
typedef float f32x4 __attribute__((ext_vector_type(4)));

__device__ __forceinline__ u16 f2bf(float f) {
    u32 u = __float_as_uint(f);
    u32 r = (u + 0x7FFFu + ((u >> 16) & 1u)) >> 16;
    return (u16)r;
}
__device__ __forceinline__ float bf2f_lo(u32 v) { return __uint_as_float(v << 16); }
__device__ __forceinline__ float bf2f_hi(u32 v) { return __uint_as_float(v & 0xFFFF0000u); }

// ============ bucketed CSR build ============
__global__ __launch_bounds__(256) void k_binA(const int* __restrict__ dst, int E,
                                              int* __restrict__ bcntT, int nblk) {
    __shared__ int h[NBKT];
    for (int i = threadIdx.x; i < NBKT; i += 256) h[i] = 0;
    __syncthreads();
    int base = blockIdx.x * 4096;
#pragma unroll
    for (int i = 0; i < 16; i++) {
        int e = base + i * 256 + threadIdx.x;
        if (e < E) atomicAdd(&h[dst[e] >> 8], 1);
    }
    __syncthreads();
    for (int i = threadIdx.x; i < NBKT; i += 256) bcntT[i * nblk + blockIdx.x] = h[i];
}

__global__ __launch_bounds__(256) void k_binT(const int* __restrict__ bcntT,
        int* __restrict__ colpre, int* __restrict__ tot, int nblk) {
    __shared__ int sh[256];
    int k = blockIdx.x, t = threadIdx.x;
    int v = (t < nblk) ? bcntT[k * nblk + t] : 0;
    sh[t] = v; __syncthreads();
    int inc = v;
    for (int o = 1; o < 256; o <<= 1) {
        int p = (t >= o) ? sh[t - o] : 0;
        __syncthreads();
        inc += p; sh[t] = inc;
        __syncthreads();
    }
    if (t < nblk) colpre[k * nblk + t] = inc - v;
    if (t == 255) tot[k] = inc;
}

__global__ __launch_bounds__(256) void k_scan_tot(const int* __restrict__ tot,
                                                  int* __restrict__ bstart, int E) {
    __shared__ int sh[256];
    int t = threadIdx.x;
    int v = (t < NBKT) ? tot[t] : 0;
    sh[t] = v; __syncthreads();
    int inc = v;
    for (int o = 1; o < 256; o <<= 1) {
        int p = (t >= o) ? sh[t - o] : 0;
        __syncthreads();
        inc += p; sh[t] = inc;
        __syncthreads();
    }
    if (t < NBKT) bstart[t] = inc - v;
    if (t == NBKT - 1) bstart[NBKT] = E;
}

__global__ __launch_bounds__(256) void k_binB(const int* __restrict__ src,
        const int* __restrict__ dst, int E, const int* __restrict__ bstart,
        const int* __restrict__ colpre, int nblk, u32* __restrict__ ebuf) {
    __shared__ int h[NBKT];
    __shared__ int base[NBKT];
    int b = blockIdx.x;
    for (int i = threadIdx.x; i < NBKT; i += 256) {
        h[i] = 0;
        base[i] = bstart[i] + colpre[i * nblk + b];
    }
    __syncthreads();
    int bb = b * 4096;
#pragma unroll
    for (int i = 0; i < 16; i++) {
        int e = bb + i * 256 + threadIdx.x;
        if (e < E) {
            int d = dst[e];
            int k = d >> 8;
            int r = atomicAdd(&h[k], 1);
            ebuf[base[k] + r] = ((u32)d << 16) | (u32)src[e];
        }
    }
}

// per-bucket: cnt + dis + bsum + per-block degree histogram (transposed, plain stores)
__global__ __launch_bounds__(256) void k_bcnt_bsum_dis(const u32* __restrict__ ebuf,
        const int* __restrict__ bstart, int* __restrict__ cnt, float* __restrict__ dis,
        int* __restrict__ bsum, int* __restrict__ dcntT, int n) {
    __shared__ int h[256];
    __shared__ int red[256];
    int k = blockIdx.x, t = threadIdx.x;
    h[t] = 0; __syncthreads();
    int beg = bstart[k], end = bstart[k + 1];
    for (int j = beg + t; j < end; j += 256)
        atomicAdd(&h[(ebuf[j] >> 16) & 255], 1);
    __syncthreads();
    int r = k * 256 + t;
    int d = h[t];
    bool valid = (r < n);
    if (valid) { cnt[r] = d; dis[r] = rsqrtf((float)d + 1.0f); }
    red[t] = valid ? d : 0;
    __syncthreads();
    h[t] = 0; __syncthreads();
    if (valid) atomicAdd(&h[min(d, 255)], 1);
    __syncthreads();
    dcntT[t * SCAN_NB + k] = h[t];    // transposed: bin-major
    for (int off = 128; off; off >>= 1) {
        if (t < off) red[t] += red[t + off];
        __syncthreads();
    }
    if (t == 0) bsum[k] = red[0];
}

// per-bin scan over 196 block-counts -> dcolpre[bin][blk], dtot[bin]
__global__ __launch_bounds__(256) void k_dscan(const int* __restrict__ dcntT,
        int* __restrict__ dcolpre, int* __restrict__ dtot) {
    __shared__ int sh[256];
    int bin = blockIdx.x, t = threadIdx.x;
    int v = (t < SCAN_NB) ? dcntT[bin * SCAN_NB + t] : 0;
    sh[t] = v; __syncthreads();
    int inc = v;
    for (int o = 1; o < 256; o <<= 1) {
        int p = (t >= o) ? sh[t - o] : 0;
        __syncthreads();
        inc += p; sh[t] = inc;
        __syncthreads();
    }
    if (t < SCAN_NB) dcolpre[bin * SCAN_NB + t] = inc - v;
    if (t == 255) dtot[bin] = inc;
}

// scan bsum (196) + scan dtot (256) -> dstart
__global__ __launch_bounds__(256) void k_scan_bsum_dhist(int* __restrict__ bsum, int nb,
        const int* __restrict__ dtot, int* __restrict__ dstart) {
    __shared__ int sh[256];
    int t = threadIdx.x;
    int v0 = (t < nb) ? bsum[t] : 0;
    sh[t] = v0; __syncthreads();
    int inc = v0;
    for (int off = 1; off < 256; off <<= 1) {
        int o = (t >= off) ? sh[t - off] : 0;
        __syncthreads();
        inc += o; sh[t] = inc;
        __syncthreads();
    }
    if (t < nb) bsum[t] = inc - v0;
    __syncthreads();
    int w0 = dtot[t];
    sh[t] = w0; __syncthreads();
    int winc = w0;
    for (int off = 1; off < 256; off <<= 1) {
        int o = (t >= off) ? sh[t - off] : 0;
        __syncthreads();
        winc += o; sh[t] = winc;
        __syncthreads();
    }
    dstart[t] = winc - w0;
}

// scan-finish + P0 prescale + perm placement (LDS cursors) + bucket adj fill
__global__ __launch_bounds__(256) void k_sfpb(const int* __restrict__ cnt,
        const int* __restrict__ bpre, int* __restrict__ rowstart,
        const float* __restrict__ x, const float* __restrict__ dis,
        float* __restrict__ p0, const u32* __restrict__ ebuf,
        const int* __restrict__ bstart, u16* __restrict__ adj,
        const int* __restrict__ dstart, const int* __restrict__ dcolpre,
        int* __restrict__ perm, int n, int E) {
    __shared__ int sh[256];
    __shared__ int cur[256];
    __shared__ int curD[256];
    int b = blockIdx.x, t = threadIdx.x;
    int i = b * 256 + t;
    int v0 = (i < n) ? cnt[i] : 0;
    sh[t] = v0;
    curD[t] = dstart[t] + dcolpre[t * SCAN_NB + b];
    __syncthreads();
    int inc = v0;
    for (int off = 1; off < 256; off <<= 1) {
        int o = (t >= off) ? sh[t - off] : 0;
        __syncthreads();
        inc += o; sh[t] = inc;
        __syncthreads();
    }
    int rs = bpre[b] + inc - v0;
    if (i < n) {
        rowstart[i] = rs;
        float dv = dis[i];
        ((float4*)p0)[i] = make_float4(dv * x[i * 3], dv * x[i * 3 + 1], dv * x[i * 3 + 2], 0.f);
        int pos = atomicAdd(&curD[min(v0, 255)], 1);   // LDS atomic, low contention
        perm[pos] = i;
    }
    if (b == gridDim.x - 1 && t == 0) rowstart[n] = E;
    cur[t] = rs;
    __syncthreads();
    int beg = bstart[b], end = bstart[b + 1];
    for (int j = beg + t; j < end; j += 256) {
        u32 e = ebuf[j];
        int p = atomicAdd(&cur[(e >> 16) & 255], 1);
        adj[p] = (u16)(e & 0xFFFF);
    }
}

// ============ weight prep ============
__global__ void k_wprep_all(const float* __restrict__ W2, const float* __restrict__ W3,
                            u16* __restrict__ w2h, u16* __restrict__ w2l,
                            u16* __restrict__ w3h, u16* __restrict__ w3l) {
    int idx = blockIdx.x * 256 + threadIdx.x;
    float w; u16* ph; u16* pl; int slot;
    if (idx < 64 * 64) {
        int o = idx >> 6, k = idx & 63;
        w = W2[k * 64 + o]; ph = w2h; pl = w2l; slot = o * 64 + k;
    } else if (idx < 64 * 64 + 256 * 64) {
        int i2 = idx - 64 * 64;
        int o = i2 >> 6, k = i2 & 63;
        w = W3[k * 256 + o]; ph = w3h; pl = w3l; slot = o * 64 + k;
    } else return;
    u16 h = f2bf(w);
    float hf = __uint_as_float((u32)h << 16);
    ph[slot] = h;
    pl[slot] = f2bf(w - hf);
}

// ============ gathers (degree-sorted via perm) ============
__global__ void k_gather3(const int* __restrict__ perm, const int* __restrict__ rowstart,
                          const u16* __restrict__ adj, const float* __restrict__ p0,
                          const float* __restrict__ dis, float* __restrict__ z, int n) {
    int gid = blockIdx.x * 256 + threadIdx.x;
    if (gid >= n) return;
    int row = perm[gid];
    const float4* P4 = (const float4*)p0;
    float4 v = P4[row];
    float a0 = v.x, a1 = v.y, a2 = v.z;
    int beg = rowstart[row], end = rowstart[row + 1];
    for (int j = beg; j < end; j++) {
        int s = (int)__builtin_nontemporal_load(adj + j);
        float4 w = P4[s];
        a0 += w.x; a1 += w.y; a2 += w.z;
    }
    float dv = dis[row];
    z[row * 3] = dv * a0; z[row * 3 + 1] = dv * a1; z[row * 3 + 2] = dv * a2;
}

__global__ __launch_bounds__(256) void k_gather64_bf16(const int* __restrict__ perm,
        const int* __restrict__ rowstart, const u16* __restrict__ adj,
        const u16* __restrict__ pb, const float* __restrict__ dis,
        u16* __restrict__ zb, int n) {
    int gid = blockIdx.x * 16 + (threadIdx.x >> 4);
    int lane = threadIdx.x & 15;
    if (gid >= n) return;
    int row = perm[gid];
    uint2 v = *((const uint2*)(pb + ((size_t)row << 6)) + lane);
    float a0 = bf2f_lo(v.x), a1 = bf2f_hi(v.x), a2 = bf2f_lo(v.y), a3 = bf2f_hi(v.y);
    int beg = rowstart[row], end = rowstart[row + 1];
    int j = beg;
    for (; j + 3 < end; j += 4) {
        int s0 = (int)__builtin_nontemporal_load(adj + j);
        int s1 = (int)__builtin_nontemporal_load(adj + j + 1);
        int s2 = (int)__builtin_nontemporal_load(adj + j + 2);
        int s3 = (int)__builtin_nontemporal_load(adj + j + 3);
        uint2 v0 = *((const uint2*)(pb + ((size_t)s0 << 6)) + lane);
        uint2 v1 = *((const uint2*)(pb + ((size_t)s1 << 6)) + lane);
        uint2 v2 = *((const uint2*)(pb + ((size_t)s2 << 6)) + lane);
        uint2 v3 = *((const uint2*)(pb + ((size_t)s3 << 6)) + lane);
        a0 += (bf2f_lo(v0.x) + bf2f_lo(v1.x)) + (bf2f_lo(v2.x) + bf2f_lo(v3.x));
        a1 += (bf2f_hi(v0.x) + bf2f_hi(v1.x)) + (bf2f_hi(v2.x) + bf2f_hi(v3.x));
        a2 += (bf2f_lo(v0.y) + bf2f_lo(v1.y)) + (bf2f_lo(v2.y) + bf2f_lo(v3.y));
        a3 += (bf2f_hi(v0.y) + bf2f_hi(v1.y)) + (bf2f_hi(v2.y) + bf2f_hi(v3.y));
    }
    for (; j < end; j++) {
        int s = (int)__builtin_nontemporal_load(adj + j);
        uint2 v0 = *((const uint2*)(pb + ((size_t)s << 6)) + lane);
        a0 += bf2f_lo(v0.x); a1 += bf2f_hi(v0.x);
        a2 += bf2f_lo(v0.y); a3 += bf2f_hi(v0.y);
    }
    float dv = dis[row];
    uint2 o;
    o.x = (u32)f2bf(a0 * dv) | ((u32)f2bf(a1 * dv) << 16);
    o.y = (u32)f2bf(a2 * dv) | ((u32)f2bf(a3 * dv) << 16);
    ((uint2*)(zb + ((size_t)row << 6)))[lane] = o;
}

__global__ void k_gather1_final(const int* __restrict__ perm, const int* __restrict__ rowstart,
                                const u16* __restrict__ adj, const float* __restrict__ q,
                                const float* __restrict__ dis, const float* __restrict__ b4,
                                float* __restrict__ out, int n) {
    int gid = blockIdx.x * 256 + threadIdx.x;
    if (gid >= n) return;
    int row = perm[gid];
    float acc = q[row];
    int beg = rowstart[row], end = rowstart[row + 1];
    for (int j = beg; j < end; j++)
        acc += q[(int)__builtin_nontemporal_load(adj + j)];
    float v = dis[row] * acc + b4[0];
    out[row] = 1.f / (1.f + expf(-v));
}

// ============ MFMA GEMM + per-block stats partials ============
__global__ __launch_bounds__(256) void k_mgemm(const u16* __restrict__ zb,
        const u16* __restrict__ wth, const u16* __restrict__ wtl,
        u16* __restrict__ t, int tstride,
        double* __restrict__ pS, double* __restrict__ pQ) {
    const int wv = threadIdx.x >> 6, lane = threadIdx.x & 63;
    const int lc = lane & 15, lk = lane >> 4;
    const int r0 = blockIdx.x * 64;
    const int col = blockIdx.y * 64 + wv * 16 + lc;

    const bf16x8* wh = (const bf16x8*)(wth + (size_t)col * 64 + lk * 8);
    const bf16x8* wl = (const bf16x8*)(wtl + (size_t)col * 64 + lk * 8);
    bf16x8 bh0 = wh[0], bh1 = wh[4];
    bf16x8 bl0 = wl[0], bl1 = wl[4];

    f32x4 acc[4] = {};
#pragma unroll
    for (int rt = 0; rt < 4; rt++) {
        const bf16x8* ap = (const bf16x8*)(zb + (size_t)(r0 + rt * 16 + lc) * 64 + lk * 8);
        bf16x8 a0 = ap[0], a1 = ap[4];
        acc[rt] = __builtin_amdgcn_mfma_f32_16x16x32_bf16(a0, bh0, acc[rt], 0, 0, 0);
        acc[rt] = __builtin_amdgcn_mfma_f32_16x16x32_bf16(a1, bh1, acc[rt], 0, 0, 0);
        acc[rt] = __builtin_amdgcn_mfma_f32_16x16x32_bf16(a0, bl0, acc[rt], 0, 0, 0);
        acc[rt] = __builtin_amdgcn_mfma_f32_16x16x32_bf16(a1, bl1, acc[rt], 0, 0, 0);
    }
#pragma unroll
    for (int rt = 0; rt < 4; rt++) {
        int rowb = r0 + rt * 16 + lk * 4;
#pragma unroll
        for (int rg = 0; rg < 4; rg++)
            t[(size_t)(rowb + rg) * tstride + col] = f2bf(acc[rt][rg]);
    }
    float s = 0.f, q = 0.f;
#pragma unroll
    for (int rt = 0; rt < 4; rt++)
#pragma unroll
        for (int rg = 0; rg < 4; rg++) { float v = acc[rt][rg]; s += v; q += v * v; }
    s += __shfl_xor(s, 16); q += __shfl_xor(q, 16);
    s += __shfl_xor(s, 32); q += __shfl_xor(q, 32);
    if (lane < 16) {
        pS[(size_t)col * NB + blockIdx.x] = (double)s;
        pQ[(size_t)col * NB + blockIdx.x] = (double)q;
    }
}

__global__ __launch_bounds__(256) void k_gemm3_stats(const float* __restrict__ z,
        const float* __restrict__ W, u16* __restrict__ t,
        double* __restrict__ pS, double* __restrict__ pQ, int n) {
    __shared__ float sH[64 * 4];
    __shared__ float sW[3 * 64];
    __shared__ double red[2 * 16 * 64];
    const int tid = threadIdx.x;
    const int r0 = blockIdx.x * 64;
    for (int i = tid; i < 192; i += 256) {
        int r = i / 3, c = i - r * 3;
        sH[r * 4 + c] = (r0 + r < n) ? z[(size_t)(r0 + r) * 3 + c] : 0.f;
    }
    if (tid < 48) ((float4*)sW)[tid] = ((const float4*)W)[tid];
    __syncthreads();
    const int tx = tid & 15, ty = tid >> 4;
    float4 acc[4];
#pragma unroll
    for (int r = 0; r < 4; r++) acc[r] = make_float4(0.f, 0.f, 0.f, 0.f);
    const float4* sW4 = (const float4*)sW;
#pragma unroll
    for (int k = 0; k < 3; k++) {
        float4 wv = sW4[k * 16 + tx];
#pragma unroll
        for (int r = 0; r < 4; r++) {
            float hs = sH[(ty * 4 + r) * 4 + k];
            acc[r].x += hs * wv.x; acc[r].y += hs * wv.y;
            acc[r].z += hs * wv.z; acc[r].w += hs * wv.w;
        }
    }
#pragma unroll
    for (int r = 0; r < 4; r++) {
        int row = r0 + ty * 4 + r;
        if (row < n) {
            uint2 o;
            o.x = (u32)f2bf(acc[r].x) | ((u32)f2bf(acc[r].y) << 16);
            o.y = (u32)f2bf(acc[r].z) | ((u32)f2bf(acc[r].w) << 16);
            *(uint2*)&t[(size_t)row * 64 + tx * 4] = o;
        }
    }
    double* redS = red;
    double* redQ = red + 16 * 64;
    double s0 = 0, s1 = 0, s2 = 0, s3 = 0, q0 = 0, q1 = 0, q2 = 0, q3 = 0;
#pragma unroll
    for (int r = 0; r < 4; r++) {
        s0 += acc[r].x; q0 += (double)acc[r].x * acc[r].x;
        s1 += acc[r].y; q1 += (double)acc[r].y * acc[r].y;
        s2 += acc[r].z; q2 += (double)acc[r].z * acc[r].z;
        s3 += acc[r].w; q3 += (double)acc[r].w * acc[r].w;
    }
    int base = ty * 64 + tx * 4;
    redS[base + 0] = s0; redS[base + 1] = s1; redS[base + 2] = s2; redS[base + 3] = s3;
    redQ[base + 0] = q0; redQ[base + 1] = q1; redQ[base + 2] = q2; redQ[base + 3] = q3;
    __syncthreads();
    if (ty == 0) {
#pragma unroll
        for (int jj = 0; jj < 4; jj++) {
            int c = tx * 4 + jj;
            double S = 0, Q = 0;
            for (int g = 0; g < 16; g++) { S += redS[g * 64 + c]; Q += redQ[g * 64 + c]; }
            pS[(size_t)c * NB + blockIdx.x] = S;
            pQ[(size_t)c * NB + blockIdx.x] = Q;
        }
    }
}

template<int F>
__global__ __launch_bounds__(256) void k_stats_fin(const double* __restrict__ pS,
        const double* __restrict__ pQ, const float* __restrict__ g,
        const float* __restrict__ be, double* __restrict__ st, int n) {
    __shared__ double shS[256], shQ[256];
    int c = blockIdx.x, t = threadIdx.x;
    double s = 0, q = 0;
    for (int i = t; i < NB; i += 256) {
        s += pS[(size_t)c * NB + i];
        q += pQ[(size_t)c * NB + i];
    }
    shS[t] = s; shQ[t] = q;
    __syncthreads();
    for (int off = 128; off; off >>= 1) {
        if (t < off) { shS[t] += shS[t + off]; shQ[t] += shQ[t + off]; }
        __syncthreads();
    }
    if (t == 0) {
        double mean = shS[0] / n;
        double var = shQ[0] / n - mean * mean;
        if (var < 0.0) var = 0.0;
        double mult = (double)g[c] / sqrt(var + 1e-5);
        st[2 * F + c] = mult;
        st[3 * F + c] = (double)be[c] - mult * mean;
    }
}

// p_bf16 = dis[v] * lrelu(mult*t + add)   (F=64)
__global__ void k_apply64(const u16* __restrict__ t, const float* __restrict__ dis,
                          const double* __restrict__ st, u16* __restrict__ p, int n) {
    int idx = blockIdx.x * 256 + threadIdx.x;
    if (idx >= n * 16) return;
    int row = idx >> 4, c = (idx & 15) * 4;
    uint2 v = ((const uint2*)t)[idx];
    float f0 = bf2f_lo(v.x), f1 = bf2f_hi(v.x), f2 = bf2f_lo(v.y), f3 = bf2f_hi(v.y);
    float m0 = (float)st[128 + c], m1 = (float)st[129 + c],
          m2 = (float)st[130 + c], m3 = (float)st[131 + c];
    float a0 = (float)st[192 + c], a1 = (float)st[193 + c],
          a2 = (float)st[194 + c], a3 = (float)st[195 + c];
    float r0 = m0 * f0 + a0; r0 = r0 > 0.f ? r0 : 0.1f * r0;
    float r1 = m1 * f1 + a1; r1 = r1 > 0.f ? r1 : 0.1f * r1;
    float r2 = m2 * f2 + a2; r2 = r2 > 0.f ? r2 : 0.1f * r2;
    float r3 = m3 * f3 + a3; r3 = r3 > 0.f ? r3 : 0.1f * r3;
    float dv = dis[row];
    uint2 o;
    o.x = (u32)f2bf(r0 * dv) | ((u32)f2bf(r1 * dv) << 16);
    o.y = (u32)f2bf(r2 * dv) | ((u32)f2bf(r3 * dv) << 16);
    ((uint2*)p)[idx] = o;
}

// layer3 apply + layer4 dot fused (t bf16, stride 256)
__global__ void k_apply3_dot(const u16* __restrict__ t, const double* __restrict__ st,
                             const float* __restrict__ dis, const float* __restrict__ W4,
                             float* __restrict__ q, int n) {
    int row = blockIdx.x * 4 + (threadIdx.x >> 6);
    int lane = threadIdx.x & 63;
    if (row >= n) return;
    uint2 v = ((const uint2*)t)[(size_t)row * 64 + lane];
    float f0 = bf2f_lo(v.x), f1 = bf2f_hi(v.x), f2 = bf2f_lo(v.y), f3 = bf2f_hi(v.y);
    int c = lane * 4;
    float m0 = (float)st[512 + c], m1 = (float)st[513 + c],
          m2 = (float)st[514 + c], m3 = (float)st[515 + c];
    float a0 = (float)st[768 + c], a1 = (float)st[769 + c],
          a2 = (float)st[770 + c], a3 = (float)st[771 + c];
    float b0 = m0 * f0 + a0; b0 = b0 > 0.f ? b0 : 0.1f * b0;
    float b1 = m1 * f1 + a1; b1 = b1 > 0.f ? b1 : 0.1f * b1;
    float b2 = m2 * f2 + a2; b2 = b2 > 0.f ? b2 : 0.1f * b2;
    float b3 = m3 * f3 + a3; b3 = b3 > 0.f ? b3 : 0.1f * b3;
    float4 w = ((const float4*)W4)[lane];
    float s = b0 * w.x + b1 * w.y + b2 * w.z + b3 * w.w;
#pragma unroll
    for (int off = 32; off; off >>= 1) s += __shfl_down(s, off);
    if (lane == 0) q[row] = dis[row] * s;
}

extern "C" void kernel_launch(void* const* d_in, const int* in_sizes, int n_in,
                              void* d_out, int out_size, void* d_ws, size_t ws_size,
                              hipStream_t stream) {
    const float* x  = (const float*)d_in[0];
    const int*   ei = (const int*)d_in[1];
    const int E = in_sizes[1] / 2;
    const int* src = ei;
    const int* dst = ei + E;
    const float* W1 = (const float*)d_in[2];
    const float* g1 = (const float*)d_in[4];
    const float* be1= (const float*)d_in[5];
    const float* W2 = (const float*)d_in[6];
    const float* g2 = (const float*)d_in[8];
    const float* be2= (const float*)d_in[9];
    const float* W3 = (const float*)d_in[10];
    const float* g3 = (const float*)d_in[12];
    const float* be3= (const float*)d_in[13];
    const float* W4 = (const float*)d_in[14];
    const float* b4 = (const float*)d_in[15];
    float* out = (float*)d_out;

    const int nblk = (E + 4095) / 4096;   // 196 for E=800k

    // workspace layout
    u16*   T    = (u16*)d_ws;                       // NP*256 bf16
    u16*   P    = T + (size_t)NP * 256;             // NN*64  bf16
    u16*   Zb   = P + (size_t)NN * 64;              // NP*64  bf16 (pad rows zeroed)
    u16*   Wt2h = Zb + (size_t)NP * 64;             // 64*64
    u16*   Wt2l = Wt2h + 64 * 64;
    u16*   Wt3h = Wt2l + 64 * 64;                   // 256*64
    u16*   Wt3l = Wt3h + 256 * 64;
    double* st  = (double*)(Wt3l + 256 * 64);       // 3*1024 doubles
    double *st0 = st, *st1 = st + 1024, *st2 = st + 2048;
    double* pS  = st + 3 * 1024;                    // 256*NB
    double* pQ  = pS + (size_t)256 * NB;            // 256*NB
    float* Z3   = (float*)(pQ + (size_t)256 * NB);  // NN*3
    float* P0   = Z3 + NN * 3;                      // NN*4
    float* Q    = P0 + NN * 4;                      // NN
    float* dis  = Q + NN;                           // NN
    int* cnt      = (int*)(dis + NN);               // NN
    int* rowstart = cnt + NN;                       // NN+1 (+pad)
    int* perm     = rowstart + NN + 8;              // NN
    u16* adj      = (u16*)(perm + NN);              // E u16
    int* bsum     = (int*)(adj + E + (E & 1));      // SCAN_NB (+pad)
    u32* ebuf     = (u32*)(bsum + SCAN_NB + 4);     // E packed edges
    int* bcntT    = (int*)(ebuf + E);               // NBKT*nblk
    int* colpre   = bcntT + NBKT * nblk;            // NBKT*nblk
    int* tot      = colpre + NBKT * nblk;           // NBKT
    int* bstart   = tot + NBKT + 4;                 // NBKT+1
    int* dcntT    = bstart + NBKT + 4;              // 256*SCAN_NB
    int* dcolpre  = dcntT + 256 * SCAN_NB;          // 256*SCAN_NB
    int* dtot     = dcolpre + 256 * SCAN_NB;        // 256
    int* dstart   = dtot + 256;                     // 256

    hipMemsetAsync(Zb + (size_t)NN * 64, 0, (size_t)(NP - NN) * 64 * sizeof(u16), stream);

    // bucketed CSR build + contention-free degree sort
    k_binA<<<nblk, 256, 0, stream>>>(dst, E, bcntT, nblk);
    k_binT<<<NBKT, 256, 0, stream>>>(bcntT, colpre, tot, nblk);
    k_scan_tot<<<1, 256, 0, stream>>>(tot, bstart, E);
    k_binB<<<nblk, 256, 0, stream>>>(src, dst, E, bstart, colpre, nblk, ebuf);
    k_bcnt_bsum_dis<<<NBKT, 256, 0, stream>>>(ebuf, bstart, cnt, dis, bsum, dcntT, NN);
    k_dscan<<<256, 256, 0, stream>>>(dcntT, dcolpre, dtot);
    k_scan_bsum_dhist<<<1, 256, 0, stream>>>(bsum, SCAN_NB, dtot, dstart);
    k_sfpb<<<SCAN_NB, 256, 0, stream>>>(cnt, bsum, rowstart, x, dis, P0, ebuf, bstart,
                                        adj, dstart, dcolpre, perm, NN, E);
    k_wprep_all<<<(64 * 64 + 256 * 64 + 255) / 256, 256, 0, stream>>>(W2, W3, Wt2h, Wt2l, Wt3h, Wt3l);

    const int rows_grid = (NN + 255) / 256;
    const int g16_grid  = (NN + 15) / 16;
    const int wave4_grid = (NN + 3) / 4;
    const int app_grid = (NN * 16 + 255) / 256;

    // ---- Layer 1 ----
    k_gather3<<<rows_grid, 256, 0, stream>>>(perm, rowstart, adj, P0, dis, Z3, NN);
    k_gemm3_stats<<<NB, 256, 0, stream>>>(Z3, W1, T, pS, pQ, NN);
    k_stats_fin<64><<<64, 256, 0, stream>>>(pS, pQ, g1, be1, st0, NN);
    k_apply64<<<app_grid, 256, 0, stream>>>(T, dis, st0, P, NN);

    // ---- Layer 2 ----
    k_gather64_bf16<<<g16_grid, 256, 0, stream>>>(perm, rowstart, adj, P, dis, Zb, NN);
    k_mgemm<<<dim3(NB, 1), 256, 0, stream>>>(Zb, Wt2h, Wt2l, T, 64, pS, pQ);
    k_stats_fin<64><<<64, 256, 0, stream>>>(pS, pQ, g2, be2, st1, NN);
    k_apply64<<<app_grid, 256, 0, stream>>>(T, dis, st1, P, NN);

    // ---- Layer 3 ----
    k_gather64_bf16<<<g16_grid, 256, 0, stream>>>(perm, rowstart, adj, P, dis, Zb, NN);
    k_mgemm<<<dim3(NB, 4), 256, 0, stream>>>(Zb, Wt3h, Wt3l, T, 256, pS, pQ);
    k_stats_fin<256><<<256, 256, 0, stream>>>(pS, pQ, g3, be3, st2, NN);

    // ---- Layer 3 apply + Layer 4 dot, then scalar gather + sigmoid ----
    k_apply3_dot<<<wave4_grid, 256, 0, stream>>>(T, st2, dis, W4, Q, NN);
    k_gather1_final<<<rows_grid, 256, 0, stream>>>(perm, rowstart, adj, Q, dis, b4, out, NN);
}

// Round 14
// 194.978 us; speedup vs baseline: 1.8218x; 1.1402x over previous
//
#include <hip/hip_runtime.h>
#include <math.h>

#define NN 50000
#define NP 50048   // padded to 64-row multiple (782 * 64)
#define NB (NP / 64)                 // 782 row-blocks
#define SCAN_NB ((NN + 255) / 256)   // 196
#define NBKT ((NN + 255) / 256)      // 196 dst-buckets of 256 rows

typedef unsigned short u16;
typedef unsigned int u32;

typedef __bf16 bf16x8 __attribute__((ext_vector_type(8)));
typedef float f32x4 __attribute__((ext_vector_type(4)));

__device__ __forceinline__ u16 f2bf(float f) {
    u32 u = __float_as_uint(f);
    u32 r = (u + 0x7FFFu + ((u >> 16) & 1u)) >> 16;
    return (u16)r;
}
__device__ __forceinline__ float bf2f_lo(u32 v) { return __uint_as_float(v << 16); }
__device__ __forceinline__ float bf2f_hi(u32 v) { return __uint_as_float(v & 0xFFFF0000u); }

// ============ bucketed CSR build ============
__global__ __launch_bounds__(256) void k_binA(const int* __restrict__ dst, int E,
                                              int* __restrict__ bcntT, int nblk) {
    __shared__ int h[NBKT];
    for (int i = threadIdx.x; i < NBKT; i += 256) h[i] = 0;
    __syncthreads();
    int base = blockIdx.x * 4096;
#pragma unroll
    for (int i = 0; i < 16; i++) {
        int e = base + i * 256 + threadIdx.x;
        if (e < E) atomicAdd(&h[dst[e] >> 8], 1);
    }
    __syncthreads();
    for (int i = threadIdx.x; i < NBKT; i += 256) bcntT[i * nblk + blockIdx.x] = h[i];
}

__global__ __launch_bounds__(256) void k_binT(const int* __restrict__ bcntT,
        int* __restrict__ colpre, int* __restrict__ tot, int nblk) {
    __shared__ int sh[256];
    int k = blockIdx.x, t = threadIdx.x;
    int v = (t < nblk) ? bcntT[k * nblk + t] : 0;
    sh[t] = v; __syncthreads();
    int inc = v;
    for (int o = 1; o < 256; o <<= 1) {
        int p = (t >= o) ? sh[t - o] : 0;
        __syncthreads();
        inc += p; sh[t] = inc;
        __syncthreads();
    }
    if (t < nblk) colpre[k * nblk + t] = inc - v;
    if (t == 255) tot[k] = inc;
}

__global__ __launch_bounds__(256) void k_scan_tot(const int* __restrict__ tot,
                                                  int* __restrict__ bstart, int E) {
    __shared__ int sh[256];
    int t = threadIdx.x;
    int v = (t < NBKT) ? tot[t] : 0;
    sh[t] = v; __syncthreads();
    int inc = v;
    for (int o = 1; o < 256; o <<= 1) {
        int p = (t >= o) ? sh[t - o] : 0;
        __syncthreads();
        inc += p; sh[t] = inc;
        __syncthreads();
    }
    if (t < NBKT) bstart[t] = inc - v;
    if (t == NBKT - 1) bstart[NBKT] = E;
}

__global__ __launch_bounds__(256) void k_binB(const int* __restrict__ src,
        const int* __restrict__ dst, int E, const int* __restrict__ bstart,
        const int* __restrict__ colpre, int nblk, u32* __restrict__ ebuf) {
    __shared__ int h[NBKT];
    __shared__ int base[NBKT];
    int b = blockIdx.x;
    for (int i = threadIdx.x; i < NBKT; i += 256) {
        h[i] = 0;
        base[i] = bstart[i] + colpre[i * nblk + b];
    }
    __syncthreads();
    int bb = b * 4096;
#pragma unroll
    for (int i = 0; i < 16; i++) {
        int e = bb + i * 256 + threadIdx.x;
        if (e < E) {
            int d = dst[e];
            int k = d >> 8;
            int r = atomicAdd(&h[k], 1);
            ebuf[base[k] + r] = ((u32)d << 16) | (u32)src[e];
        }
    }
}

// per-bucket: cnt + dis + bsum (fused, LDS atomics only)
__global__ __launch_bounds__(256) void k_bcnt_bsum_dis(const u32* __restrict__ ebuf,
        const int* __restrict__ bstart, int* __restrict__ cnt, float* __restrict__ dis,
        int* __restrict__ bsum, int n) {
    __shared__ int h[256];
    __shared__ int red[256];
    int k = blockIdx.x, t = threadIdx.x;
    h[t] = 0; __syncthreads();
    int beg = bstart[k], end = bstart[k + 1];
    for (int j = beg + t; j < end; j += 256)
        atomicAdd(&h[(ebuf[j] >> 16) & 255], 1);
    __syncthreads();
    int r = k * 256 + t;
    int d = h[t];
    bool valid = (r < n);
    if (valid) { cnt[r] = d; dis[r] = rsqrtf((float)d + 1.0f); }
    red[t] = valid ? d : 0;
    __syncthreads();
    for (int off = 128; off; off >>= 1) {
        if (t < off) red[t] += red[t + off];
        __syncthreads();
    }
    if (t == 0) bsum[k] = red[0];
}

__global__ void k_scan_bsum(int* __restrict__ bsum, int nb) {
    __shared__ int sh[256];
    int t = threadIdx.x;
    int v0 = (t < nb) ? bsum[t] : 0;
    sh[t] = v0; __syncthreads();
    int inc = v0;
    for (int off = 1; off < 256; off <<= 1) {
        int o = (t >= off) ? sh[t - off] : 0;
        __syncthreads();
        inc += o; sh[t] = inc;
        __syncthreads();
    }
    if (t < nb) bsum[t] = inc - v0;
}

// scan-finish + P0 prescale + bucket adj fill (fused; same 256-row blocking)
__global__ __launch_bounds__(256) void k_sfpb(const int* __restrict__ cnt,
        const int* __restrict__ bpre, int* __restrict__ rowstart,
        const float* __restrict__ x, const float* __restrict__ dis,
        float* __restrict__ p0, const u32* __restrict__ ebuf,
        const int* __restrict__ bstart, u16* __restrict__ adj, int n, int E) {
    __shared__ int sh[256];
    __shared__ int cur[256];
    int b = blockIdx.x, t = threadIdx.x;
    int i = b * 256 + t;
    int v0 = (i < n) ? cnt[i] : 0;
    sh[t] = v0; __syncthreads();
    int inc = v0;
    for (int off = 1; off < 256; off <<= 1) {
        int o = (t >= off) ? sh[t - off] : 0;
        __syncthreads();
        inc += o; sh[t] = inc;
        __syncthreads();
    }
    int rs = bpre[b] + inc - v0;
    if (i < n) {
        rowstart[i] = rs;
        float dv = dis[i];
        ((float4*)p0)[i] = make_float4(dv * x[i * 3], dv * x[i * 3 + 1], dv * x[i * 3 + 2], 0.f);
    }
    if (b == gridDim.x - 1 && t == 0) rowstart[n] = E;
    cur[t] = rs;
    __syncthreads();
    int beg = bstart[b], end = bstart[b + 1];
    for (int j = beg + t; j < end; j += 256) {
        u32 e = ebuf[j];
        int p = atomicAdd(&cur[(e >> 16) & 255], 1);
        adj[p] = (u16)(e & 0xFFFF);
    }
}

// ============ weight prep ============
__global__ void k_wprep_all(const float* __restrict__ W2, const float* __restrict__ W3,
                            u16* __restrict__ w2h, u16* __restrict__ w2l,
                            u16* __restrict__ w3h, u16* __restrict__ w3l) {
    int idx = blockIdx.x * 256 + threadIdx.x;
    float w; u16* ph; u16* pl; int slot;
    if (idx < 64 * 64) {
        int o = idx >> 6, k = idx & 63;
        w = W2[k * 64 + o]; ph = w2h; pl = w2l; slot = o * 64 + k;
    } else if (idx < 64 * 64 + 256 * 64) {
        int i2 = idx - 64 * 64;
        int o = i2 >> 6, k = i2 & 63;
        w = W3[k * 256 + o]; ph = w3h; pl = w3l; slot = o * 64 + k;
    } else return;
    u16 h = f2bf(w);
    float hf = __uint_as_float((u32)h << 16);
    ph[slot] = h;
    pl[slot] = f2bf(w - hf);
}

// ============ gathers (direct row-blocked; proven coalesced form) ============
__global__ void k_gather3(const int* __restrict__ rowstart, const u16* __restrict__ adj,
                          const float* __restrict__ p0, const float* __restrict__ dis,
                          float* __restrict__ z, int n) {
    int row = blockIdx.x * 256 + threadIdx.x;
    if (row >= n) return;
    const float4* P4 = (const float4*)p0;
    float4 v = P4[row];
    float a0 = v.x, a1 = v.y, a2 = v.z;
    int beg = rowstart[row], end = rowstart[row + 1];
    for (int j = beg; j < end; j++) {
        int s = (int)__builtin_nontemporal_load(adj + j);
        float4 w = P4[s];
        a0 += w.x; a1 += w.y; a2 += w.z;
    }
    float dv = dis[row];
    z[row * 3] = dv * a0; z[row * 3 + 1] = dv * a1; z[row * 3 + 2] = dv * a2;
}

__global__ __launch_bounds__(256) void k_gather64_bf16(const int* __restrict__ rowstart,
        const u16* __restrict__ adj, const u16* __restrict__ pb,
        const float* __restrict__ dis, u16* __restrict__ zb, int n) {
    int row = blockIdx.x * 16 + (threadIdx.x >> 4);
    int lane = threadIdx.x & 15;
    if (row >= n) return;
    uint2 v = *((const uint2*)(pb + ((size_t)row << 6)) + lane);
    float a0 = bf2f_lo(v.x), a1 = bf2f_hi(v.x), a2 = bf2f_lo(v.y), a3 = bf2f_hi(v.y);
    int beg = rowstart[row], end = rowstart[row + 1];
    int j = beg;
    for (; j + 3 < end; j += 4) {
        int s0 = (int)__builtin_nontemporal_load(adj + j);
        int s1 = (int)__builtin_nontemporal_load(adj + j + 1);
        int s2 = (int)__builtin_nontemporal_load(adj + j + 2);
        int s3 = (int)__builtin_nontemporal_load(adj + j + 3);
        uint2 v0 = *((const uint2*)(pb + ((size_t)s0 << 6)) + lane);
        uint2 v1 = *((const uint2*)(pb + ((size_t)s1 << 6)) + lane);
        uint2 v2 = *((const uint2*)(pb + ((size_t)s2 << 6)) + lane);
        uint2 v3 = *((const uint2*)(pb + ((size_t)s3 << 6)) + lane);
        a0 += (bf2f_lo(v0.x) + bf2f_lo(v1.x)) + (bf2f_lo(v2.x) + bf2f_lo(v3.x));
        a1 += (bf2f_hi(v0.x) + bf2f_hi(v1.x)) + (bf2f_hi(v2.x) + bf2f_hi(v3.x));
        a2 += (bf2f_lo(v0.y) + bf2f_lo(v1.y)) + (bf2f_lo(v2.y) + bf2f_lo(v3.y));
        a3 += (bf2f_hi(v0.y) + bf2f_hi(v1.y)) + (bf2f_hi(v2.y) + bf2f_hi(v3.y));
    }
    for (; j < end; j++) {
        int s = (int)__builtin_nontemporal_load(adj + j);
        uint2 v0 = *((const uint2*)(pb + ((size_t)s << 6)) + lane);
        a0 += bf2f_lo(v0.x); a1 += bf2f_hi(v0.x);
        a2 += bf2f_lo(v0.y); a3 += bf2f_hi(v0.y);
    }
    float dv = dis[row];
    uint2 o;
    o.x = (u32)f2bf(a0 * dv) | ((u32)f2bf(a1 * dv) << 16);
    o.y = (u32)f2bf(a2 * dv) | ((u32)f2bf(a3 * dv) << 16);
    ((uint2*)(zb + ((size_t)row << 6)))[lane] = o;
}

__global__ void k_gather1_final(const int* __restrict__ rowstart, const u16* __restrict__ adj,
                                const float* __restrict__ q, const float* __restrict__ dis,
                                const float* __restrict__ b4, float* __restrict__ out, int n) {
    int row = blockIdx.x * 256 + threadIdx.x;
    if (row >= n) return;
    float acc = q[row];
    int beg = rowstart[row], end = rowstart[row + 1];
    for (int j = beg; j < end; j++)
        acc += q[(int)__builtin_nontemporal_load(adj + j)];
    float v = dis[row] * acc + b4[0];
    out[row] = 1.f / (1.f + expf(-v));
}

// ============ MFMA GEMM + per-block stats partials ============
__global__ __launch_bounds__(256) void k_mgemm(const u16* __restrict__ zb,
        const u16* __restrict__ wth, const u16* __restrict__ wtl,
        u16* __restrict__ t, int tstride,
        double* __restrict__ pS, double* __restrict__ pQ) {
    const int wv = threadIdx.x >> 6, lane = threadIdx.x & 63;
    const int lc = lane & 15, lk = lane >> 4;
    const int r0 = blockIdx.x * 64;
    const int col = blockIdx.y * 64 + wv * 16 + lc;

    const bf16x8* wh = (const bf16x8*)(wth + (size_t)col * 64 + lk * 8);
    const bf16x8* wl = (const bf16x8*)(wtl + (size_t)col * 64 + lk * 8);
    bf16x8 bh0 = wh[0], bh1 = wh[4];
    bf16x8 bl0 = wl[0], bl1 = wl[4];

    f32x4 acc[4] = {};
#pragma unroll
    for (int rt = 0; rt < 4; rt++) {
        const bf16x8* ap = (const bf16x8*)(zb + (size_t)(r0 + rt * 16 + lc) * 64 + lk * 8);
        bf16x8 a0 = ap[0], a1 = ap[4];
        acc[rt] = __builtin_amdgcn_mfma_f32_16x16x32_bf16(a0, bh0, acc[rt], 0, 0, 0);
        acc[rt] = __builtin_amdgcn_mfma_f32_16x16x32_bf16(a1, bh1, acc[rt], 0, 0, 0);
        acc[rt] = __builtin_amdgcn_mfma_f32_16x16x32_bf16(a0, bl0, acc[rt], 0, 0, 0);
        acc[rt] = __builtin_amdgcn_mfma_f32_16x16x32_bf16(a1, bl1, acc[rt], 0, 0, 0);
    }
#pragma unroll
    for (int rt = 0; rt < 4; rt++) {
        int rowb = r0 + rt * 16 + lk * 4;
#pragma unroll
        for (int rg = 0; rg < 4; rg++)
            t[(size_t)(rowb + rg) * tstride + col] = f2bf(acc[rt][rg]);
    }
    float s = 0.f, q = 0.f;
#pragma unroll
    for (int rt = 0; rt < 4; rt++)
#pragma unroll
        for (int rg = 0; rg < 4; rg++) { float v = acc[rt][rg]; s += v; q += v * v; }
    s += __shfl_xor(s, 16); q += __shfl_xor(q, 16);
    s += __shfl_xor(s, 32); q += __shfl_xor(q, 32);
    if (lane < 16) {
        pS[(size_t)col * NB + blockIdx.x] = (double)s;
        pQ[(size_t)col * NB + blockIdx.x] = (double)q;
    }
}

__global__ __launch_bounds__(256) void k_gemm3_stats(const float* __restrict__ z,
        const float* __restrict__ W, u16* __restrict__ t,
        double* __restrict__ pS, double* __restrict__ pQ, int n) {
    __shared__ float sH[64 * 4];
    __shared__ float sW[3 * 64];
    __shared__ double red[2 * 16 * 64];
    const int tid = threadIdx.x;
    const int r0 = blockIdx.x * 64;
    for (int i = tid; i < 192; i += 256) {
        int r = i / 3, c = i - r * 3;
        sH[r * 4 + c] = (r0 + r < n) ? z[(size_t)(r0 + r) * 3 + c] : 0.f;
    }
    if (tid < 48) ((float4*)sW)[tid] = ((const float4*)W)[tid];
    __syncthreads();
    const int tx = tid & 15, ty = tid >> 4;
    float4 acc[4];
#pragma unroll
    for (int r = 0; r < 4; r++) acc[r] = make_float4(0.f, 0.f, 0.f, 0.f);
    const float4* sW4 = (const float4*)sW;
#pragma unroll
    for (int k = 0; k < 3; k++) {
        float4 wv = sW4[k * 16 + tx];
#pragma unroll
        for (int r = 0; r < 4; r++) {
            float hs = sH[(ty * 4 + r) * 4 + k];
            acc[r].x += hs * wv.x; acc[r].y += hs * wv.y;
            acc[r].z += hs * wv.z; acc[r].w += hs * wv.w;
        }
    }
#pragma unroll
    for (int r = 0; r < 4; r++) {
        int row = r0 + ty * 4 + r;
        if (row < n) {
            uint2 o;
            o.x = (u32)f2bf(acc[r].x) | ((u32)f2bf(acc[r].y) << 16);
            o.y = (u32)f2bf(acc[r].z) | ((u32)f2bf(acc[r].w) << 16);
            *(uint2*)&t[(size_t)row * 64 + tx * 4] = o;
        }
    }
    double* redS = red;
    double* redQ = red + 16 * 64;
    double s0 = 0, s1 = 0, s2 = 0, s3 = 0, q0 = 0, q1 = 0, q2 = 0, q3 = 0;
#pragma unroll
    for (int r = 0; r < 4; r++) {
        s0 += acc[r].x; q0 += (double)acc[r].x * acc[r].x;
        s1 += acc[r].y; q1 += (double)acc[r].y * acc[r].y;
        s2 += acc[r].z; q2 += (double)acc[r].z * acc[r].z;
        s3 += acc[r].w; q3 += (double)acc[r].w * acc[r].w;
    }
    int base = ty * 64 + tx * 4;
    redS[base + 0] = s0; redS[base + 1] = s1; redS[base + 2] = s2; redS[base + 3] = s3;
    redQ[base + 0] = q0; redQ[base + 1] = q1; redQ[base + 2] = q2; redQ[base + 3] = q3;
    __syncthreads();
    if (ty == 0) {
#pragma unroll
        for (int jj = 0; jj < 4; jj++) {
            int c = tx * 4 + jj;
            double S = 0, Q = 0;
            for (int g = 0; g < 16; g++) { S += redS[g * 64 + c]; Q += redQ[g * 64 + c]; }
            pS[(size_t)c * NB + blockIdx.x] = S;
            pQ[(size_t)c * NB + blockIdx.x] = Q;
        }
    }
}

template<int F>
__global__ __launch_bounds__(256) void k_stats_fin(const double* __restrict__ pS,
        const double* __restrict__ pQ, const float* __restrict__ g,
        const float* __restrict__ be, double* __restrict__ st, int n) {
    __shared__ double shS[256], shQ[256];
    int c = blockIdx.x, t = threadIdx.x;
    double s = 0, q = 0;
    for (int i = t; i < NB; i += 256) {
        s += pS[(size_t)c * NB + i];
        q += pQ[(size_t)c * NB + i];
    }
    shS[t] = s; shQ[t] = q;
    __syncthreads();
    for (int off = 128; off; off >>= 1) {
        if (t < off) { shS[t] += shS[t + off]; shQ[t] += shQ[t + off]; }
        __syncthreads();
    }
    if (t == 0) {
        double mean = shS[0] / n;
        double var = shQ[0] / n - mean * mean;
        if (var < 0.0) var = 0.0;
        double mult = (double)g[c] / sqrt(var + 1e-5);
        st[2 * F + c] = mult;
        st[3 * F + c] = (double)be[c] - mult * mean;
    }
}

// p_bf16 = dis[v] * lrelu(mult*t + add)   (F=64)
__global__ void k_apply64(const u16* __restrict__ t, const float* __restrict__ dis,
                          const double* __restrict__ st, u16* __restrict__ p, int n) {
    int idx = blockIdx.x * 256 + threadIdx.x;
    if (idx >= n * 16) return;
    int row = idx >> 4, c = (idx & 15) * 4;
    uint2 v = ((const uint2*)t)[idx];
    float f0 = bf2f_lo(v.x), f1 = bf2f_hi(v.x), f2 = bf2f_lo(v.y), f3 = bf2f_hi(v.y);
    float m0 = (float)st[128 + c], m1 = (float)st[129 + c],
          m2 = (float)st[130 + c], m3 = (float)st[131 + c];
    float a0 = (float)st[192 + c], a1 = (float)st[193 + c],
          a2 = (float)st[194 + c], a3 = (float)st[195 + c];
    float r0 = m0 * f0 + a0; r0 = r0 > 0.f ? r0 : 0.1f * r0;
    float r1 = m1 * f1 + a1; r1 = r1 > 0.f ? r1 : 0.1f * r1;
    float r2 = m2 * f2 + a2; r2 = r2 > 0.f ? r2 : 0.1f * r2;
    float r3 = m3 * f3 + a3; r3 = r3 > 0.f ? r3 : 0.1f * r3;
    float dv = dis[row];
    uint2 o;
    o.x = (u32)f2bf(r0 * dv) | ((u32)f2bf(r1 * dv) << 16);
    o.y = (u32)f2bf(r2 * dv) | ((u32)f2bf(r3 * dv) << 16);
    ((uint2*)p)[idx] = o;
}

// layer3 apply + layer4 dot fused (t bf16, stride 256)
__global__ void k_apply3_dot(const u16* __restrict__ t, const double* __restrict__ st,
                             const float* __restrict__ dis, const float* __restrict__ W4,
                             float* __restrict__ q, int n) {
    int row = blockIdx.x * 4 + (threadIdx.x >> 6);
    int lane = threadIdx.x & 63;
    if (row >= n) return;
    uint2 v = ((const uint2*)t)[(size_t)row * 64 + lane];
    float f0 = bf2f_lo(v.x), f1 = bf2f_hi(v.x), f2 = bf2f_lo(v.y), f3 = bf2f_hi(v.y);
    int c = lane * 4;
    float m0 = (float)st[512 + c], m1 = (float)st[513 + c],
          m2 = (float)st[514 + c], m3 = (float)st[515 + c];
    float a0 = (float)st[768 + c], a1 = (float)st[769 + c],
          a2 = (float)st[770 + c], a3 = (float)st[771 + c];
    float b0 = m0 * f0 + a0; b0 = b0 > 0.f ? b0 : 0.1f * b0;
    float b1 = m1 * f1 + a1; b1 = b1 > 0.f ? b1 : 0.1f * b1;
    float b2 = m2 * f2 + a2; b2 = b2 > 0.f ? b2 : 0.1f * b2;
    float b3 = m3 * f3 + a3; b3 = b3 > 0.f ? b3 : 0.1f * b3;
    float4 w = ((const float4*)W4)[lane];
    float s = b0 * w.x + b1 * w.y + b2 * w.z + b3 * w.w;
#pragma unroll
    for (int off = 32; off; off >>= 1) s += __shfl_down(s, off);
    if (lane == 0) q[row] = dis[row] * s;
}

extern "C" void kernel_launch(void* const* d_in, const int* in_sizes, int n_in,
                              void* d_out, int out_size, void* d_ws, size_t ws_size,
                              hipStream_t stream) {
    const float* x  = (const float*)d_in[0];
    const int*   ei = (const int*)d_in[1];
    const int E = in_sizes[1] / 2;
    const int* src = ei;
    const int* dst = ei + E;
    const float* W1 = (const float*)d_in[2];
    const float* g1 = (const float*)d_in[4];
    const float* be1= (const float*)d_in[5];
    const float* W2 = (const float*)d_in[6];
    const float* g2 = (const float*)d_in[8];
    const float* be2= (const float*)d_in[9];
    const float* W3 = (const float*)d_in[10];
    const float* g3 = (const float*)d_in[12];
    const float* be3= (const float*)d_in[13];
    const float* W4 = (const float*)d_in[14];
    const float* b4 = (const float*)d_in[15];
    float* out = (float*)d_out;

    const int nblk = (E + 4095) / 4096;   // 196 for E=800k

    // workspace layout
    u16*   T    = (u16*)d_ws;                       // NP*256 bf16
    u16*   P    = T + (size_t)NP * 256;             // NN*64  bf16
    u16*   Zb   = P + (size_t)NN * 64;              // NP*64  bf16 (pad rows zeroed)
    u16*   Wt2h = Zb + (size_t)NP * 64;             // 64*64
    u16*   Wt2l = Wt2h + 64 * 64;
    u16*   Wt3h = Wt2l + 64 * 64;                   // 256*64
    u16*   Wt3l = Wt3h + 256 * 64;
    double* st  = (double*)(Wt3l + 256 * 64);       // 3*1024 doubles
    double *st0 = st, *st1 = st + 1024, *st2 = st + 2048;
    double* pS  = st + 3 * 1024;                    // 256*NB
    double* pQ  = pS + (size_t)256 * NB;            // 256*NB
    float* Z3   = (float*)(pQ + (size_t)256 * NB);  // NN*3
    float* P0   = Z3 + NN * 3;                      // NN*4
    float* Q    = P0 + NN * 4;                      // NN
    float* dis  = Q + NN;                           // NN
    int* cnt      = (int*)(dis + NN);               // NN
    int* rowstart = cnt + NN;                       // NN+1 (+pad)
    u16* adj      = (u16*)(rowstart + NN + 8);      // E u16
    int* bsum     = (int*)(adj + E + (E & 1));      // SCAN_NB (+pad)
    u32* ebuf     = (u32*)(bsum + SCAN_NB + 4);     // E packed edges
    int* bcntT    = (int*)(ebuf + E);               // NBKT*nblk
    int* colpre   = bcntT + NBKT * nblk;            // NBKT*nblk
    int* tot      = colpre + NBKT * nblk;           // NBKT
    int* bstart   = tot + NBKT + 4;                 // NBKT+1

    hipMemsetAsync(Zb + (size_t)NN * 64, 0, (size_t)(NP - NN) * 64 * sizeof(u16), stream);

    // bucketed CSR build (fused, all stages parallel, no degree sort)
    k_binA<<<nblk, 256, 0, stream>>>(dst, E, bcntT, nblk);
    k_binT<<<NBKT, 256, 0, stream>>>(bcntT, colpre, tot, nblk);
    k_scan_tot<<<1, 256, 0, stream>>>(tot, bstart, E);
    k_binB<<<nblk, 256, 0, stream>>>(src, dst, E, bstart, colpre, nblk, ebuf);
    k_bcnt_bsum_dis<<<NBKT, 256, 0, stream>>>(ebuf, bstart, cnt, dis, bsum, NN);
    k_scan_bsum<<<1, 256, 0, stream>>>(bsum, SCAN_NB);
    k_sfpb<<<SCAN_NB, 256, 0, stream>>>(cnt, bsum, rowstart, x, dis, P0, ebuf, bstart,
                                        adj, NN, E);
    k_wprep_all<<<(64 * 64 + 256 * 64 + 255) / 256, 256, 0, stream>>>(W2, W3, Wt2h, Wt2l, Wt3h, Wt3l);

    const int rows_grid = (NN + 255) / 256;
    const int g16_grid  = (NN + 15) / 16;
    const int wave4_grid = (NN + 3) / 4;
    const int app_grid = (NN * 16 + 255) / 256;

    // ---- Layer 1 ----
    k_gather3<<<rows_grid, 256, 0, stream>>>(rowstart, adj, P0, dis, Z3, NN);
    k_gemm3_stats<<<NB, 256, 0, stream>>>(Z3, W1, T, pS, pQ, NN);
    k_stats_fin<64><<<64, 256, 0, stream>>>(pS, pQ, g1, be1, st0, NN);
    k_apply64<<<app_grid, 256, 0, stream>>>(T, dis, st0, P, NN);

    // ---- Layer 2 ----
    k_gather64_bf16<<<g16_grid, 256, 0, stream>>>(rowstart, adj, P, dis, Zb, NN);
    k_mgemm<<<dim3(NB, 1), 256, 0, stream>>>(Zb, Wt2h, Wt2l, T, 64, pS, pQ);
    k_stats_fin<64><<<64, 256, 0, stream>>>(pS, pQ, g2, be2, st1, NN);
    k_apply64<<<app_grid, 256, 0, stream>>>(T, dis, st1, P, NN);

    // ---- Layer 3 ----
    k_gather64_bf16<<<g16_grid, 256, 0, stream>>>(rowstart, adj, P, dis, Zb, NN);
    k_mgemm<<<dim3(NB, 4), 256, 0, stream>>>(Zb, Wt3h, Wt3l, T, 256, pS, pQ);
    k_stats_fin<256><<<256, 256, 0, stream>>>(pS, pQ, g3, be3, st2, NN);

    // ---- Layer 3 apply + Layer 4 dot, then scalar gather + sigmoid ----
    k_apply3_dot<<<wave4_grid, 256, 0, stream>>>(T, st2, dis, W4, Q, NN);
    k_gather1_final<<<rows_grid, 256, 0, stream>>>(rowstart, adj, Q, dis, b4, out, NN);
}

// Round 15
// 189.694 us; speedup vs baseline: 1.8726x; 1.0279x over previous
//
#include <hip/hip_runtime.h>
#include <math.h>

#define NN 50000
#define NP 50048   // padded to 64-row multiple (782 * 64)
#define NB (NP / 64)                 // 782 row-blocks
#define SCAN_NB ((NN + 255) / 256)   // 196
#define NBKT ((NN + 255) / 256)      // 196 dst-buckets of 256 rows

typedef unsigned short u16;
typedef unsigned int u32;

typedef __bf16 bf16x8 __attribute__((ext_vector_type(8)));
typedef float f32x4 __attribute__((ext_vector_type(4)));

__device__ __forceinline__ u16 f2bf(float f) {
    u32 u = __float_as_uint(f);
    u32 r = (u + 0x7FFFu + ((u >> 16) & 1u)) >> 16;
    return (u16)r;
}
__device__ __forceinline__ float bf2f_lo(u32 v) { return __uint_as_float(v << 16); }
__device__ __forceinline__ float bf2f_hi(u32 v) { return __uint_as_float(v & 0xFFFF0000u); }

// ============ bucketed CSR build (+ fused weight prep in tail blocks) ============
__global__ __launch_bounds__(256) void k_binA_wprep(const int* __restrict__ dst, int E,
        int* __restrict__ bcntT, int nblk,
        const float* __restrict__ W2, const float* __restrict__ W3,
        u16* __restrict__ w2h, u16* __restrict__ w2l,
        u16* __restrict__ w3h, u16* __restrict__ w3l) {
    if (blockIdx.x >= (unsigned)nblk) {
        int idx = (blockIdx.x - nblk) * 256 + threadIdx.x;
        float w; u16* ph; u16* pl; int slot;
        if (idx < 64 * 64) {
            int o = idx >> 6, k = idx & 63;
            w = W2[k * 64 + o]; ph = w2h; pl = w2l; slot = o * 64 + k;
        } else if (idx < 64 * 64 + 256 * 64) {
            int i2 = idx - 64 * 64;
            int o = i2 >> 6, k = i2 & 63;
            w = W3[k * 256 + o]; ph = w3h; pl = w3l; slot = o * 64 + k;
        } else return;
        u16 h = f2bf(w);
        float hf = __uint_as_float((u32)h << 16);
        ph[slot] = h;
        pl[slot] = f2bf(w - hf);
        return;
    }
    __shared__ int h[NBKT];
    for (int i = threadIdx.x; i < NBKT; i += 256) h[i] = 0;
    __syncthreads();
    int base = blockIdx.x * 4096;
#pragma unroll
    for (int i = 0; i < 16; i++) {
        int e = base + i * 256 + threadIdx.x;
        if (e < E) atomicAdd(&h[dst[e] >> 8], 1);
    }
    __syncthreads();
    for (int i = threadIdx.x; i < NBKT; i += 256) bcntT[i * nblk + blockIdx.x] = h[i];
}

__global__ __launch_bounds__(256) void k_binT(const int* __restrict__ bcntT,
        int* __restrict__ colpre, int* __restrict__ tot, int nblk) {
    __shared__ int sh[256];
    int k = blockIdx.x, t = threadIdx.x;
    int v = (t < nblk) ? bcntT[k * nblk + t] : 0;
    sh[t] = v; __syncthreads();
    int inc = v;
    for (int o = 1; o < 256; o <<= 1) {
        int p = (t >= o) ? sh[t - o] : 0;
        __syncthreads();
        inc += p; sh[t] = inc;
        __syncthreads();
    }
    if (t < nblk) colpre[k * nblk + t] = inc - v;
    if (t == 255) tot[k] = inc;
}

__global__ __launch_bounds__(256) void k_scan_tot(const int* __restrict__ tot,
                                                  int* __restrict__ bstart, int E) {
    __shared__ int sh[256];
    int t = threadIdx.x;
    int v = (t < NBKT) ? tot[t] : 0;
    sh[t] = v; __syncthreads();
    int inc = v;
    for (int o = 1; o < 256; o <<= 1) {
        int p = (t >= o) ? sh[t - o] : 0;
        __syncthreads();
        inc += p; sh[t] = inc;
        __syncthreads();
    }
    if (t < NBKT) bstart[t] = inc - v;
    if (t == NBKT - 1) bstart[NBKT] = E;
}

__global__ __launch_bounds__(256) void k_binB(const int* __restrict__ src,
        const int* __restrict__ dst, int E, const int* __restrict__ bstart,
        const int* __restrict__ colpre, int nblk, u32* __restrict__ ebuf) {
    __shared__ int h[NBKT];
    __shared__ int base[NBKT];
    int b = blockIdx.x;
    for (int i = threadIdx.x; i < NBKT; i += 256) {
        h[i] = 0;
        base[i] = bstart[i] + colpre[i * nblk + b];
    }
    __syncthreads();
    int bb = b * 4096;
#pragma unroll
    for (int i = 0; i < 16; i++) {
        int e = bb + i * 256 + threadIdx.x;
        if (e < E) {
            int d = dst[e];
            int k = d >> 8;
            int r = atomicAdd(&h[k], 1);
            ebuf[base[k] + r] = ((u32)d << 16) | (u32)src[e];
        }
    }
}

// per-bucket: cnt + dis + bsum (fused, LDS atomics only)
__global__ __launch_bounds__(256) void k_bcnt_bsum_dis(const u32* __restrict__ ebuf,
        const int* __restrict__ bstart, int* __restrict__ cnt, float* __restrict__ dis,
        int* __restrict__ bsum, int n) {
    __shared__ int h[256];
    __shared__ int red[256];
    int k = blockIdx.x, t = threadIdx.x;
    h[t] = 0; __syncthreads();
    int beg = bstart[k], end = bstart[k + 1];
    for (int j = beg + t; j < end; j += 256)
        atomicAdd(&h[(ebuf[j] >> 16) & 255], 1);
    __syncthreads();
    int r = k * 256 + t;
    int d = h[t];
    bool valid = (r < n);
    if (valid) { cnt[r] = d; dis[r] = rsqrtf((float)d + 1.0f); }
    red[t] = valid ? d : 0;
    __syncthreads();
    for (int off = 128; off; off >>= 1) {
        if (t < off) red[t] += red[t + off];
        __syncthreads();
    }
    if (t == 0) bsum[k] = red[0];
}

__global__ void k_scan_bsum(int* __restrict__ bsum, int nb) {
    __shared__ int sh[256];
    int t = threadIdx.x;
    int v0 = (t < nb) ? bsum[t] : 0;
    sh[t] = v0; __syncthreads();
    int inc = v0;
    for (int off = 1; off < 256; off <<= 1) {
        int o = (t >= off) ? sh[t - off] : 0;
        __syncthreads();
        inc += o; sh[t] = inc;
        __syncthreads();
    }
    if (t < nb) bsum[t] = inc - v0;
}

// scan-finish + P0 prescale + bucket adj fill (fused; same 256-row blocking)
__global__ __launch_bounds__(256) void k_sfpb(const int* __restrict__ cnt,
        const int* __restrict__ bpre, int* __restrict__ rowstart,
        const float* __restrict__ x, const float* __restrict__ dis,
        float* __restrict__ p0, const u32* __restrict__ ebuf,
        const int* __restrict__ bstart, u16* __restrict__ adj, int n, int E) {
    __shared__ int sh[256];
    __shared__ int cur[256];
    int b = blockIdx.x, t = threadIdx.x;
    int i = b * 256 + t;
    int v0 = (i < n) ? cnt[i] : 0;
    sh[t] = v0; __syncthreads();
    int inc = v0;
    for (int off = 1; off < 256; off <<= 1) {
        int o = (t >= off) ? sh[t - off] : 0;
        __syncthreads();
        inc += o; sh[t] = inc;
        __syncthreads();
    }
    int rs = bpre[b] + inc - v0;
    if (i < n) {
        rowstart[i] = rs;
        float dv = dis[i];
        ((float4*)p0)[i] = make_float4(dv * x[i * 3], dv * x[i * 3 + 1], dv * x[i * 3 + 2], 0.f);
    }
    if (b == gridDim.x - 1 && t == 0) rowstart[n] = E;
    cur[t] = rs;
    __syncthreads();
    int beg = bstart[b], end = bstart[b + 1];
    for (int j = beg + t; j < end; j += 256) {
        u32 e = ebuf[j];
        int p = atomicAdd(&cur[(e >> 16) & 255], 1);
        adj[p] = (u16)(e & 0xFFFF);
    }
}

// ============ gathers ============
__global__ void k_gather3(const int* __restrict__ rowstart, const u16* __restrict__ adj,
                          const float* __restrict__ p0, const float* __restrict__ dis,
                          float* __restrict__ z, int n) {
    int row = blockIdx.x * 256 + threadIdx.x;
    if (row >= n) return;
    const float4* P4 = (const float4*)p0;
    float4 v = P4[row];
    float a0 = v.x, a1 = v.y, a2 = v.z;
    int beg = rowstart[row], end = rowstart[row + 1];
    for (int j = beg; j < end; j++) {
        int s = (int)__builtin_nontemporal_load(adj + j);
        float4 w = P4[s];
        a0 += w.x; a1 += w.y; a2 += w.z;
    }
    float dv = dis[row];
    z[row * 3] = dv * a0; z[row * 3 + 1] = dv * a1; z[row * 3 + 2] = dv * a2;
}

// 64-feat gather with fused BN apply: reads T (bf16, stride 64) + st (mult/add),
// computes acc = sum_s dis[s]*lrelu(m*t[s]+a), writes Zb = bf16(dis[row]*acc)
__global__ __launch_bounds__(256) void k_gather64_bn(const int* __restrict__ rowstart,
        const u16* __restrict__ adj, const u16* __restrict__ tb,
        const float* __restrict__ dis, const double* __restrict__ st,
        u16* __restrict__ zb, int n) {
    int row = blockIdx.x * 16 + (threadIdx.x >> 4);
    int lane = threadIdx.x & 15;
    if (row >= n) return;
    int c = lane * 4;
    const float m0 = (float)st[128 + c], m1 = (float)st[129 + c],
                m2 = (float)st[130 + c], m3 = (float)st[131 + c];
    const float b0 = (float)st[192 + c], b1 = (float)st[193 + c],
                b2 = (float)st[194 + c], b3 = (float)st[195 + c];
    float a0, a1, a2, a3;
    {   // self-loop
        uint2 v = *((const uint2*)(tb + ((size_t)row << 6)) + lane);
        float ds = dis[row];
        float r0 = m0 * bf2f_lo(v.x) + b0; r0 = r0 > 0.f ? r0 : 0.1f * r0;
        float r1 = m1 * bf2f_hi(v.x) + b1; r1 = r1 > 0.f ? r1 : 0.1f * r1;
        float r2 = m2 * bf2f_lo(v.y) + b2; r2 = r2 > 0.f ? r2 : 0.1f * r2;
        float r3 = m3 * bf2f_hi(v.y) + b3; r3 = r3 > 0.f ? r3 : 0.1f * r3;
        a0 = r0 * ds; a1 = r1 * ds; a2 = r2 * ds; a3 = r3 * ds;
    }
    int beg = rowstart[row], end = rowstart[row + 1];
    int j = beg;
    for (; j + 3 < end; j += 4) {
        int s0 = (int)__builtin_nontemporal_load(adj + j);
        int s1 = (int)__builtin_nontemporal_load(adj + j + 1);
        int s2 = (int)__builtin_nontemporal_load(adj + j + 2);
        int s3 = (int)__builtin_nontemporal_load(adj + j + 3);
        uint2 v0 = *((const uint2*)(tb + ((size_t)s0 << 6)) + lane);
        uint2 v1 = *((const uint2*)(tb + ((size_t)s1 << 6)) + lane);
        uint2 v2 = *((const uint2*)(tb + ((size_t)s2 << 6)) + lane);
        uint2 v3 = *((const uint2*)(tb + ((size_t)s3 << 6)) + lane);
        float d0 = dis[s0], d1 = dis[s1], d2 = dis[s2], d3 = dis[s3];
        float r;
        r = m0 * bf2f_lo(v0.x) + b0; r = r > 0.f ? r : 0.1f * r; a0 += r * d0;
        r = m1 * bf2f_hi(v0.x) + b1; r = r > 0.f ? r : 0.1f * r; a1 += r * d0;
        r = m2 * bf2f_lo(v0.y) + b2; r = r > 0.f ? r : 0.1f * r; a2 += r * d0;
        r = m3 * bf2f_hi(v0.y) + b3; r = r > 0.f ? r : 0.1f * r; a3 += r * d0;
        r = m0 * bf2f_lo(v1.x) + b0; r = r > 0.f ? r : 0.1f * r; a0 += r * d1;
        r = m1 * bf2f_hi(v1.x) + b1; r = r > 0.f ? r : 0.1f * r; a1 += r * d1;
        r = m2 * bf2f_lo(v1.y) + b2; r = r > 0.f ? r : 0.1f * r; a2 += r * d1;
        r = m3 * bf2f_hi(v1.y) + b3; r = r > 0.f ? r : 0.1f * r; a3 += r * d1;
        r = m0 * bf2f_lo(v2.x) + b0; r = r > 0.f ? r : 0.1f * r; a0 += r * d2;
        r = m1 * bf2f_hi(v2.x) + b1; r = r > 0.f ? r : 0.1f * r; a1 += r * d2;
        r = m2 * bf2f_lo(v2.y) + b2; r = r > 0.f ? r : 0.1f * r; a2 += r * d2;
        r = m3 * bf2f_hi(v2.y) + b3; r = r > 0.f ? r : 0.1f * r; a3 += r * d2;
        r = m0 * bf2f_lo(v3.x) + b0; r = r > 0.f ? r : 0.1f * r; a0 += r * d3;
        r = m1 * bf2f_hi(v3.x) + b1; r = r > 0.f ? r : 0.1f * r; a1 += r * d3;
        r = m2 * bf2f_lo(v3.y) + b2; r = r > 0.f ? r : 0.1f * r; a2 += r * d3;
        r = m3 * bf2f_hi(v3.y) + b3; r = r > 0.f ? r : 0.1f * r; a3 += r * d3;
    }
    for (; j < end; j++) {
        int s = (int)__builtin_nontemporal_load(adj + j);
        uint2 v0 = *((const uint2*)(tb + ((size_t)s << 6)) + lane);
        float ds = dis[s];
        float r;
        r = m0 * bf2f_lo(v0.x) + b0; r = r > 0.f ? r : 0.1f * r; a0 += r * ds;
        r = m1 * bf2f_hi(v0.x) + b1; r = r > 0.f ? r : 0.1f * r; a1 += r * ds;
        r = m2 * bf2f_lo(v0.y) + b2; r = r > 0.f ? r : 0.1f * r; a2 += r * ds;
        r = m3 * bf2f_hi(v0.y) + b3; r = r > 0.f ? r : 0.1f * r; a3 += r * ds;
    }
    float dv = dis[row];
    uint2 o;
    o.x = (u32)f2bf(a0 * dv) | ((u32)f2bf(a1 * dv) << 16);
    o.y = (u32)f2bf(a2 * dv) | ((u32)f2bf(a3 * dv) << 16);
    ((uint2*)(zb + ((size_t)row << 6)))[lane] = o;
}

__global__ void k_gather1_final(const int* __restrict__ rowstart, const u16* __restrict__ adj,
                                const float* __restrict__ q, const float* __restrict__ dis,
                                const float* __restrict__ b4, float* __restrict__ out, int n) {
    int row = blockIdx.x * 256 + threadIdx.x;
    if (row >= n) return;
    float acc = q[row];
    int beg = rowstart[row], end = rowstart[row + 1];
    for (int j = beg; j < end; j++)
        acc += q[(int)__builtin_nontemporal_load(adj + j)];
    float v = dis[row] * acc + b4[0];
    out[row] = 1.f / (1.f + expf(-v));
}

// ============ MFMA GEMM + per-block stats partials ============
__global__ __launch_bounds__(256) void k_mgemm(const u16* __restrict__ zb,
        const u16* __restrict__ wth, const u16* __restrict__ wtl,
        u16* __restrict__ t, int tstride,
        double* __restrict__ pS, double* __restrict__ pQ) {
    const int wv = threadIdx.x >> 6, lane = threadIdx.x & 63;
    const int lc = lane & 15, lk = lane >> 4;
    const int r0 = blockIdx.x * 64;
    const int col = blockIdx.y * 64 + wv * 16 + lc;

    const bf16x8* wh = (const bf16x8*)(wth + (size_t)col * 64 + lk * 8);
    const bf16x8* wl = (const bf16x8*)(wtl + (size_t)col * 64 + lk * 8);
    bf16x8 bh0 = wh[0], bh1 = wh[4];
    bf16x8 bl0 = wl[0], bl1 = wl[4];

    f32x4 acc[4] = {};
#pragma unroll
    for (int rt = 0; rt < 4; rt++) {
        const bf16x8* ap = (const bf16x8*)(zb + (size_t)(r0 + rt * 16 + lc) * 64 + lk * 8);
        bf16x8 a0 = ap[0], a1 = ap[4];
        acc[rt] = __builtin_amdgcn_mfma_f32_16x16x32_bf16(a0, bh0, acc[rt], 0, 0, 0);
        acc[rt] = __builtin_amdgcn_mfma_f32_16x16x32_bf16(a1, bh1, acc[rt], 0, 0, 0);
        acc[rt] = __builtin_amdgcn_mfma_f32_16x16x32_bf16(a0, bl0, acc[rt], 0, 0, 0);
        acc[rt] = __builtin_amdgcn_mfma_f32_16x16x32_bf16(a1, bl1, acc[rt], 0, 0, 0);
    }
#pragma unroll
    for (int rt = 0; rt < 4; rt++) {
        int rowb = r0 + rt * 16 + lk * 4;
#pragma unroll
        for (int rg = 0; rg < 4; rg++)
            t[(size_t)(rowb + rg) * tstride + col] = f2bf(acc[rt][rg]);
    }
    float s = 0.f, q = 0.f;
#pragma unroll
    for (int rt = 0; rt < 4; rt++)
#pragma unroll
        for (int rg = 0; rg < 4; rg++) { float v = acc[rt][rg]; s += v; q += v * v; }
    s += __shfl_xor(s, 16); q += __shfl_xor(q, 16);
    s += __shfl_xor(s, 32); q += __shfl_xor(q, 32);
    if (lane < 16) {
        pS[(size_t)col * NB + blockIdx.x] = (double)s;
        pQ[(size_t)col * NB + blockIdx.x] = (double)q;
    }
}

__global__ __launch_bounds__(256) void k_gemm3_stats(const float* __restrict__ z,
        const float* __restrict__ W, u16* __restrict__ t,
        double* __restrict__ pS, double* __restrict__ pQ, int n) {
    __shared__ float sH[64 * 4];
    __shared__ float sW[3 * 64];
    __shared__ double red[2 * 16 * 64];
    const int tid = threadIdx.x;
    const int r0 = blockIdx.x * 64;
    for (int i = tid; i < 192; i += 256) {
        int r = i / 3, c = i - r * 3;
        sH[r * 4 + c] = (r0 + r < n) ? z[(size_t)(r0 + r) * 3 + c] : 0.f;
    }
    if (tid < 48) ((float4*)sW)[tid] = ((const float4*)W)[tid];
    __syncthreads();
    const int tx = tid & 15, ty = tid >> 4;
    float4 acc[4];
#pragma unroll
    for (int r = 0; r < 4; r++) acc[r] = make_float4(0.f, 0.f, 0.f, 0.f);
    const float4* sW4 = (const float4*)sW;
#pragma unroll
    for (int k = 0; k < 3; k++) {
        float4 wv = sW4[k * 16 + tx];
#pragma unroll
        for (int r = 0; r < 4; r++) {
            float hs = sH[(ty * 4 + r) * 4 + k];
            acc[r].x += hs * wv.x; acc[r].y += hs * wv.y;
            acc[r].z += hs * wv.z; acc[r].w += hs * wv.w;
        }
    }
#pragma unroll
    for (int r = 0; r < 4; r++) {
        int row = r0 + ty * 4 + r;
        if (row < n) {
            uint2 o;
            o.x = (u32)f2bf(acc[r].x) | ((u32)f2bf(acc[r].y) << 16);
            o.y = (u32)f2bf(acc[r].z) | ((u32)f2bf(acc[r].w) << 16);
            *(uint2*)&t[(size_t)row * 64 + tx * 4] = o;
        }
    }
    double* redS = red;
    double* redQ = red + 16 * 64;
    double s0 = 0, s1 = 0, s2 = 0, s3 = 0, q0 = 0, q1 = 0, q2 = 0, q3 = 0;
#pragma unroll
    for (int r = 0; r < 4; r++) {
        s0 += acc[r].x; q0 += (double)acc[r].x * acc[r].x;
        s1 += acc[r].y; q1 += (double)acc[r].y * acc[r].y;
        s2 += acc[r].z; q2 += (double)acc[r].z * acc[r].z;
        s3 += acc[r].w; q3 += (double)acc[r].w * acc[r].w;
    }
    int base = ty * 64 + tx * 4;
    redS[base + 0] = s0; redS[base + 1] = s1; redS[base + 2] = s2; redS[base + 3] = s3;
    redQ[base + 0] = q0; redQ[base + 1] = q1; redQ[base + 2] = q2; redQ[base + 3] = q3;
    __syncthreads();
    if (ty == 0) {
#pragma unroll
        for (int jj = 0; jj < 4; jj++) {
            int c = tx * 4 + jj;
            double S = 0, Q = 0;
            for (int g = 0; g < 16; g++) { S += redS[g * 64 + c]; Q += redQ[g * 64 + c]; }
            pS[(size_t)c * NB + blockIdx.x] = S;
            pQ[(size_t)c * NB + blockIdx.x] = Q;
        }
    }
}

template<int F>
__global__ __launch_bounds__(256) void k_stats_fin(const double* __restrict__ pS,
        const double* __restrict__ pQ, const float* __restrict__ g,
        const float* __restrict__ be, double* __restrict__ st, int n) {
    __shared__ double shS[256], shQ[256];
    int c = blockIdx.x, t = threadIdx.x;
    double s = 0, q = 0;
    for (int i = t; i < NB; i += 256) {
        s += pS[(size_t)c * NB + i];
        q += pQ[(size_t)c * NB + i];
    }
    shS[t] = s; shQ[t] = q;
    __syncthreads();
    for (int off = 128; off; off >>= 1) {
        if (t < off) { shS[t] += shS[t + off]; shQ[t] += shQ[t + off]; }
        __syncthreads();
    }
    if (t == 0) {
        double mean = shS[0] / n;
        double var = shQ[0] / n - mean * mean;
        if (var < 0.0) var = 0.0;
        double mult = (double)g[c] / sqrt(var + 1e-5);
        st[2 * F + c] = mult;
        st[3 * F + c] = (double)be[c] - mult * mean;
    }
}

// layer3 apply + layer4 dot fused (t bf16, stride 256)
__global__ void k_apply3_dot(const u16* __restrict__ t, const double* __restrict__ st,
                             const float* __restrict__ dis, const float* __restrict__ W4,
                             float* __restrict__ q, int n) {
    int row = blockIdx.x * 4 + (threadIdx.x >> 6);
    int lane = threadIdx.x & 63;
    if (row >= n) return;
    uint2 v = ((const uint2*)t)[(size_t)row * 64 + lane];
    float f0 = bf2f_lo(v.x), f1 = bf2f_hi(v.x), f2 = bf2f_lo(v.y), f3 = bf2f_hi(v.y);
    int c = lane * 4;
    float m0 = (float)st[512 + c], m1 = (float)st[513 + c],
          m2 = (float)st[514 + c], m3 = (float)st[515 + c];
    float a0 = (float)st[768 + c], a1 = (float)st[769 + c],
          a2 = (float)st[770 + c], a3 = (float)st[771 + c];
    float b0 = m0 * f0 + a0; b0 = b0 > 0.f ? b0 : 0.1f * b0;
    float b1 = m1 * f1 + a1; b1 = b1 > 0.f ? b1 : 0.1f * b1;
    float b2 = m2 * f2 + a2; b2 = b2 > 0.f ? b2 : 0.1f * b2;
    float b3 = m3 * f3 + a3; b3 = b3 > 0.f ? b3 : 0.1f * b3;
    float4 w = ((const float4*)W4)[lane];
    float s = b0 * w.x + b1 * w.y + b2 * w.z + b3 * w.w;
#pragma unroll
    for (int off = 32; off; off >>= 1) s += __shfl_down(s, off);
    if (lane == 0) q[row] = dis[row] * s;
}

extern "C" void kernel_launch(void* const* d_in, const int* in_sizes, int n_in,
                              void* d_out, int out_size, void* d_ws, size_t ws_size,
                              hipStream_t stream) {
    const float* x  = (const float*)d_in[0];
    const int*   ei = (const int*)d_in[1];
    const int E = in_sizes[1] / 2;
    const int* src = ei;
    const int* dst = ei + E;
    const float* W1 = (const float*)d_in[2];
    const float* g1 = (const float*)d_in[4];
    const float* be1= (const float*)d_in[5];
    const float* W2 = (const float*)d_in[6];
    const float* g2 = (const float*)d_in[8];
    const float* be2= (const float*)d_in[9];
    const float* W3 = (const float*)d_in[10];
    const float* g3 = (const float*)d_in[12];
    const float* be3= (const float*)d_in[13];
    const float* W4 = (const float*)d_in[14];
    const float* b4 = (const float*)d_in[15];
    float* out = (float*)d_out;

    const int nblk = (E + 4095) / 4096;   // 196 for E=800k

    // workspace layout
    u16*   T    = (u16*)d_ws;                       // NP*256 bf16
    u16*   Zb   = T + (size_t)NP * 256;             // NP*64 bf16 (pad rows zeroed)
    u16*   Wt2h = Zb + (size_t)NP * 64;             // 64*64
    u16*   Wt2l = Wt2h + 64 * 64;
    u16*   Wt3h = Wt2l + 64 * 64;                   // 256*64
    u16*   Wt3l = Wt3h + 256 * 64;
    double* st  = (double*)(Wt3l + 256 * 64);       // 3*1024 doubles
    double *st0 = st, *st1 = st + 1024, *st2 = st + 2048;
    double* pS  = st + 3 * 1024;                    // 256*NB
    double* pQ  = pS + (size_t)256 * NB;            // 256*NB
    float* Z3   = (float*)(pQ + (size_t)256 * NB);  // NN*3
    float* P0   = Z3 + NN * 3;                      // NN*4
    float* Q    = P0 + NN * 4;                      // NN
    float* dis  = Q + NN;                           // NN
    int* cnt      = (int*)(dis + NN);               // NN
    int* rowstart = cnt + NN;                       // NN+1 (+pad)
    u16* adj      = (u16*)(rowstart + NN + 8);      // E u16
    int* bsum     = (int*)(adj + E + (E & 1));      // SCAN_NB (+pad)
    u32* ebuf     = (u32*)(bsum + SCAN_NB + 4);     // E packed edges
    int* bcntT    = (int*)(ebuf + E);               // NBKT*nblk
    int* colpre   = bcntT + NBKT * nblk;            // NBKT*nblk
    int* tot      = colpre + NBKT * nblk;           // NBKT
    int* bstart   = tot + NBKT + 4;                 // NBKT+1

    hipMemsetAsync(Zb + (size_t)NN * 64, 0, (size_t)(NP - NN) * 64 * sizeof(u16), stream);

    // bucketed CSR build (fused; weight prep in tail blocks of binA)
    k_binA_wprep<<<nblk + 80, 256, 0, stream>>>(dst, E, bcntT, nblk,
                                                W2, W3, Wt2h, Wt2l, Wt3h, Wt3l);
    k_binT<<<NBKT, 256, 0, stream>>>(bcntT, colpre, tot, nblk);
    k_scan_tot<<<1, 256, 0, stream>>>(tot, bstart, E);
    k_binB<<<nblk, 256, 0, stream>>>(src, dst, E, bstart, colpre, nblk, ebuf);
    k_bcnt_bsum_dis<<<NBKT, 256, 0, stream>>>(ebuf, bstart, cnt, dis, bsum, NN);
    k_scan_bsum<<<1, 256, 0, stream>>>(bsum, SCAN_NB);
    k_sfpb<<<SCAN_NB, 256, 0, stream>>>(cnt, bsum, rowstart, x, dis, P0, ebuf, bstart,
                                        adj, NN, E);

    const int rows_grid = (NN + 255) / 256;
    const int g16_grid  = (NN + 15) / 16;
    const int wave4_grid = (NN + 3) / 4;

    // ---- Layer 1 ----
    k_gather3<<<rows_grid, 256, 0, stream>>>(rowstart, adj, P0, dis, Z3, NN);
    k_gemm3_stats<<<NB, 256, 0, stream>>>(Z3, W1, T, pS, pQ, NN);
    k_stats_fin<64><<<64, 256, 0, stream>>>(pS, pQ, g1, be1, st0, NN);

    // ---- Layer 2 (gather reads T with fused BN apply) ----
    k_gather64_bn<<<g16_grid, 256, 0, stream>>>(rowstart, adj, T, dis, st0, Zb, NN);
    k_mgemm<<<dim3(NB, 1), 256, 0, stream>>>(Zb, Wt2h, Wt2l, T, 64, pS, pQ);
    k_stats_fin<64><<<64, 256, 0, stream>>>(pS, pQ, g2, be2, st1, NN);

    // ---- Layer 3 ----
    k_gather64_bn<<<g16_grid, 256, 0, stream>>>(rowstart, adj, T, dis, st1, Zb, NN);
    k_mgemm<<<dim3(NB, 4), 256, 0, stream>>>(Zb, Wt3h, Wt3l, T, 256, pS, pQ);
    k_stats_fin<256><<<256, 256, 0, stream>>>(pS, pQ, g3, be3, st2, NN);

    // ---- Layer 3 apply + Layer 4 dot, then scalar gather + sigmoid ----
    k_apply3_dot<<<wave4_grid, 256, 0, stream>>>(T, st2, dis, W4, Q, NN);
    k_gather1_final<<<rows_grid, 256, 0, stream>>>(rowstart, adj, Q, dis, b4, out, NN);
}